// Round 14
// baseline (125.369 us; speedup 1.0000x reference)
//
#include <hip/hip_runtime.h>
#include <hip/hip_bf16.h>

#define BB 2
#define CC 64
#define HH 128
#define WW 128
#define OC 64
#define HW (HH * WW)

typedef __attribute__((ext_vector_type(8))) short bf16x8;
typedef __attribute__((ext_vector_type(4))) float f32x4;

__device__ __forceinline__ unsigned short bfbits(float f) {
    __hip_bfloat16 h = __float2bfloat16(f);
    return __builtin_bit_cast(unsigned short, h);
}
__device__ __forceinline__ float frombits(unsigned short u) {
    unsigned int v = ((unsigned int)u) << 16;
    return __builtin_bit_cast(float, v);
}
__device__ __forceinline__ int iclamp(int v, int lo, int hi) {
    return v < lo ? lo : (v > hi ? hi : v);
}

// ---------------- Wc -> bf16 A-fragment pack ----------------
// K-order k'' = n*64 + c. Fragment order: idx = ((a*4 + m)*16 + r)*8 + j
// Lane (r,kb) of tile m at step s reads 16B at (s*4+kb)*512 + m*128 + r*8.
__global__ __launch_bounds__(256) void wpack2(const float* __restrict__ Wc,
                                              unsigned short* __restrict__ Wb3)
{
    const int idx = blockIdx.x * 256 + threadIdx.x;
    if (idx < OC * 576) {
        const int j = idx & 7;
        const int r = (idx >> 3) & 15;
        const int m = (idx >> 7) & 3;
        const int a = idx >> 9;
        const int n = a >> 3;
        const int c = (a & 7) * 8 + j;
        const int oc = m * 16 + r;
        Wb3[idx] = bfbits(Wc[oc * 576 + c * 9 + n]);
    }
}

// ---------------- main kernel: cooperative offsets, independent wave GEMM ------
// R14 change vs R13: fit the body under the (256,4) VGPR cap of 64
// (cap = 256/min_waves, measured R2-R11) to regain the 37-45% occupancy regime
// (R3/R5 pattern) instead of (256,2)'s 20-26%. Register cuts: A-fragments in
// pairs, s-loop unroll 1 (one step's gathers in flight; TLP covers latency).
__global__ __launch_bounds__(256, 4) void dcn_wave(
    const float* __restrict__ x,
    const float* __restrict__ Wp,
    const float* __restrict__ bp,
    const unsigned short* __restrict__ Wb3,
    float* __restrict__ out)
{
    // [0,18432): part fp32 [8 grp][32 pos][18]   (union: reduction scratch)
    // [18432,19008): mi  short[288]   slot = n*32 + pos
    // [19008,21312): mw  ushort4[288]
    __shared__ __align__(16) unsigned char smraw[21312];
    float*          part = (float*)smraw;
    short*          mi   = (short*)(smraw + 18432);
    ushort4*        mw   = (ushort4*)(smraw + 19008);

    const int t   = threadIdx.x;
    const int bxr = (blockIdx.x & 7) * 128 + (blockIdx.x >> 3);  // XCD chunk swizzle
    const int b   = bxr >> 9;
    const int i   = (bxr >> 2) & 127;
    const int j0  = (bxr & 3) << 5;      // 32-pos segment base

    // ---------------- phase 0a: offset-conv partials (R3/R5-verified) ------------
    {
        const int grp = t >> 5;          // 8 groups of 8 channels
        const int pp  = t & 31;
        const int j   = j0 + pp;
        float acc[18];
#pragma unroll
        for (int o = 0; o < 18; ++o) acc[o] = 0.f;
        const float* xg = x + (b * CC + grp * 8) * HW;
        for (int c = 0; c < 8; ++c) {
            float xv[9];
#pragma unroll
            for (int dx = 0; dx < 3; ++dx) {
                const int ii = i + dx - 1;
                const bool okx = (unsigned)ii < (unsigned)HH;
#pragma unroll
                for (int dy = 0; dy < 3; ++dy) {
                    const int jj = j + dy - 1;
                    const bool ok = okx && ((unsigned)jj < (unsigned)WW);
                    xv[dx * 3 + dy] = ok ? xg[c * HW + ii * WW + jj] : 0.f;
                }
            }
            const float* wp = Wp + (grp * 8 + c) * 9;
#pragma unroll
            for (int o = 0; o < 18; ++o) {
                const float* w = wp + o * 576;
#pragma unroll
                for (int k = 0; k < 9; ++k)
                    acc[o] = fmaf(xv[k], w[k], acc[o]);
            }
        }
#pragma unroll
        for (int o = 0; o < 18; ++o)
            part[grp * 576 + pp * 18 + o] = acc[o];
    }
    __syncthreads();

    // ---------------- phase 0b: metadata, 288 slots ----------------
    {
        auto mkmeta = [&](int slot) {
            const int n   = slot >> 5;
            const int pos = slot & 31;
            const int kx  = n / 3, ky = n - kx * 3;
            float offx = bp[n], offy = bp[9 + n];
#pragma unroll
            for (int g = 0; g < 8; ++g) {
                offx += part[g * 576 + pos * 18 + n];
                offy += part[g * 576 + pos * 18 + 9 + n];
            }
            const float px = offx + (float)(kx - 1) + (float)(i + 1);
            const float py = offy + (float)(ky - 1) + (float)(j0 + pos + 1);
            const float flx = floorf(px), fly = floorf(py);
            const float qltx = fminf(fmaxf(flx,       0.f), 129.f);
            const float qlty = fminf(fmaxf(fly,       0.f), 129.f);
            const float qrbx = fminf(fmaxf(flx + 1.f, 0.f), 129.f);
            const float qrby = fminf(fmaxf(fly + 1.f, 0.f), 129.f);
            const float pxc  = fminf(fmaxf(px, 0.f), 129.f);
            const float pyc  = fminf(fmaxf(py, 0.f), 129.f);
            const float gx0 = 1.f + (qltx - pxc), gx1 = 1.f - (qrbx - pxc);
            const float gy0 = 1.f + (qlty - pyc), gy1 = 1.f - (qrby - pyc);
            const int rx0 = (int)qltx - 1, rx1 = (int)qrbx - 1;
            const int ry0 = (int)qlty - 1, ry1 = (int)qrby - 1;
            const bool vx0 = (unsigned)rx0 < (unsigned)HH, vx1 = (unsigned)rx1 < (unsigned)HH;
            const bool vy0 = (unsigned)ry0 < (unsigned)WW, vy1 = (unsigned)ry1 < (unsigned)WW;
            const float w0 = (vx0 && vy0) ? gx0 * gy0 : 0.f;   // +0
            const float w1 = (vx1 && vy1) ? gx1 * gy1 : 0.f;   // +129
            const float w2 = (vx0 && vy1) ? gx0 * gy1 : 0.f;   // +1
            const float w3 = (vx1 && vy0) ? gx1 * gy0 : 0.f;   // +128
            mi[slot] = (short)(rx0 * WW + ry0);
            mw[slot] = make_ushort4(bfbits(w0), bfbits(w1), bfbits(w2), bfbits(w3));
        };
        mkmeta(t);
        if (t < 32) mkmeta(256 + t);
    }
    __syncthreads();

    // ---------------- independent per-wave gather + MFMA (no barriers) ----------
    const int l    = t & 63;
    const int w_   = t >> 6;
    const int sw   = w_ >> 1;          // strip within segment (0/1)
    const int half = w_ & 1;           // K half
    const int r    = l & 15;
    const int kb   = l >> 4;
    const int posl = sw * 16 + r;      // 0..31
    const float* xb = x + b * (CC * HW);
    const unsigned short* wbase = Wb3 + (half * 36 + kb) * 512 + r * 8;

    f32x4 acc0 = {0.f, 0.f, 0.f, 0.f};
    f32x4 acc1 = {0.f, 0.f, 0.f, 0.f};
    f32x4 acc2 = {0.f, 0.f, 0.f, 0.f};
    f32x4 acc3 = {0.f, 0.f, 0.f, 0.f};

#pragma unroll 1
    for (int s = 0; s < 9; ++s) {
        const int a  = half * 36 + s * 4 + kb;   // k''-octet
        const int n  = a >> 3;
        const int c0 = (a & 7) * 8;
        const int slot = n * 32 + posl;
        const int base = (int)mi[slot];
        const ushort4 wq = mw[slot];
        const float w0 = frombits(wq.x), w1 = frombits(wq.y);
        const float w2 = frombits(wq.z), w3 = frombits(wq.w);
        const int i0 = iclamp(base,       0, HW - 1);
        const int i1 = iclamp(base + 129, 0, HW - 1);
        const int i2 = iclamp(base + 1,   0, HW - 1);
        const int i3 = iclamp(base + 128, 0, HW - 1);
        const float* p = xb + c0 * HW;
        bf16x8 bfrag;
#pragma unroll
        for (int j = 0; j < 8; ++j) {
            float v = p[i0] * w0;
            v = fmaf(p[i1], w1, v);
            v = fmaf(p[i2], w2, v);
            v = fmaf(p[i3], w3, v);
            bfrag[j] = (short)bfbits(v);
            p += HW;
        }
        const unsigned short* wp8 = wbase + s * 2048;
        // A-fragments in pairs: 8 live regs instead of 16 (VGPR cap 64)
        {
            const bf16x8 af0 = *(const bf16x8*)(wp8);
            const bf16x8 af1 = *(const bf16x8*)(wp8 + 128);
            acc0 = __builtin_amdgcn_mfma_f32_16x16x32_bf16(af0, bfrag, acc0, 0, 0, 0);
            acc1 = __builtin_amdgcn_mfma_f32_16x16x32_bf16(af1, bfrag, acc1, 0, 0, 0);
        }
        {
            const bf16x8 af2 = *(const bf16x8*)(wp8 + 256);
            const bf16x8 af3 = *(const bf16x8*)(wp8 + 384);
            acc2 = __builtin_amdgcn_mfma_f32_16x16x32_bf16(af2, bfrag, acc2, 0, 0, 0);
            acc3 = __builtin_amdgcn_mfma_f32_16x16x32_bf16(af3, bfrag, acc3, 0, 0, 0);
        }
    }

    // ---------------- K-half reduction through LDS + store ----------------
    float* red = part;   // phase-0 partials dead
    if (half) {
        *(f32x4*)&red[sw * 1024 + 0 * 256 + l * 4] = acc0;
        *(f32x4*)&red[sw * 1024 + 1 * 256 + l * 4] = acc1;
        *(f32x4*)&red[sw * 1024 + 2 * 256 + l * 4] = acc2;
        *(f32x4*)&red[sw * 1024 + 3 * 256 + l * 4] = acc3;
    }
    __syncthreads();
    if (!half) {
        acc0 += *(const f32x4*)&red[sw * 1024 + 0 * 256 + l * 4];
        acc1 += *(const f32x4*)&red[sw * 1024 + 1 * 256 + l * 4];
        acc2 += *(const f32x4*)&red[sw * 1024 + 2 * 256 + l * 4];
        acc3 += *(const f32x4*)&red[sw * 1024 + 3 * 256 + l * 4];
        const int jcol = j0 + posl;
        f32x4 av[4] = {acc0, acc1, acc2, acc3};
#pragma unroll
        for (int m = 0; m < 4; ++m)
#pragma unroll
            for (int reg = 0; reg < 4; ++reg) {
                const int oc = m * 16 + kb * 4 + reg;
                out[((b * OC + oc) * HH + i) * WW + jcol] = av[m][reg];
            }
    }
}

// ---------------- fallback: R5 kernel (proven 116us, no workspace) ----------------

struct Meta { int i0, i1, i2, i3; float w0, w1, w2, w3; };

__device__ __forceinline__ void offset_phase(
    const float* __restrict__ x, const float* __restrict__ Wp,
    const float* __restrict__ bp, float* __restrict__ smem,
    int b, int i, int j0, int t, Meta& M0, Meta& M1)
{
    {
        const int grp = t >> 5;
        const int pp  = t & 31;
        const int j   = j0 + pp;
        float part[18];
#pragma unroll
        for (int o = 0; o < 18; ++o) part[o] = 0.f;
        const float* xg = x + (b * CC + grp * 8) * HW;
        for (int c = 0; c < 8; ++c) {
            float xv[9];
#pragma unroll
            for (int dx = 0; dx < 3; ++dx) {
                const int ii = i + dx - 1;
                const bool okx = (unsigned)ii < (unsigned)HH;
#pragma unroll
                for (int dy = 0; dy < 3; ++dy) {
                    const int jj = j + dy - 1;
                    const bool ok = okx && ((unsigned)jj < (unsigned)WW);
                    xv[dx * 3 + dy] = ok ? xg[c * HW + ii * WW + jj] : 0.f;
                }
            }
            const float* wp = Wp + (grp * 8 + c) * 9;
#pragma unroll
            for (int o = 0; o < 18; ++o) {
                const float* w = wp + o * 576;
#pragma unroll
                for (int k = 0; k < 9; ++k)
                    part[o] = fmaf(xv[k], w[k], part[o]);
            }
        }
#pragma unroll
        for (int o = 0; o < 18; ++o)
            smem[grp * 576 + pp * 18 + o] = part[o];
    }
    __syncthreads();

    auto mkmeta = [&](int pos, int n) -> Meta {
        const int kx = n / 3, ky = n - kx * 3;
        float offx = bp[n], offy = bp[9 + n];
#pragma unroll
        for (int g = 0; g < 8; ++g) {
            offx += smem[g * 576 + pos * 18 + n];
            offy += smem[g * 576 + pos * 18 + 9 + n];
        }
        const float px = offx + (float)(kx - 1) + (float)(i + 1);
        const float py = offy + (float)(ky - 1) + (float)(j0 + pos + 1);
        const float flx = floorf(px), fly = floorf(py);
        const float qltx = fminf(fmaxf(flx,       0.f), 129.f);
        const float qlty = fminf(fmaxf(fly,       0.f), 129.f);
        const float qrbx = fminf(fmaxf(flx + 1.f, 0.f), 129.f);
        const float qrby = fminf(fmaxf(fly + 1.f, 0.f), 129.f);
        const float pxc  = fminf(fmaxf(px, 0.f), 129.f);
        const float pyc  = fminf(fmaxf(py, 0.f), 129.f);
        const float gx0 = 1.f + (qltx - pxc), gx1 = 1.f - (qrbx - pxc);
        const float gy0 = 1.f + (qlty - pyc), gy1 = 1.f - (qrby - pyc);
        const int rx0 = (int)qltx - 1, rx1 = (int)qrbx - 1;
        const int ry0 = (int)qlty - 1, ry1 = (int)qrby - 1;
        const bool vx0 = (unsigned)rx0 < (unsigned)HH, vx1 = (unsigned)rx1 < (unsigned)HH;
        const bool vy0 = (unsigned)ry0 < (unsigned)WW, vy1 = (unsigned)ry1 < (unsigned)WW;
        Meta M;
        M.i0 = (vx0 && vy0) ? rx0 * WW + ry0 : 0;  M.w0 = (vx0 && vy0) ? gx0 * gy0 : 0.f;
        M.i1 = (vx1 && vy1) ? rx1 * WW + ry1 : 0;  M.w1 = (vx1 && vy1) ? gx1 * gy1 : 0.f;
        M.i2 = (vx0 && vy1) ? rx0 * WW + ry1 : 0;  M.w2 = (vx0 && vy1) ? gx0 * gy1 : 0.f;
        M.i3 = (vx1 && vy0) ? rx1 * WW + ry0 : 0;  M.w3 = (vx1 && vy0) ? gx1 * gy0 : 0.f;
        return M;
    };

    M0 = mkmeta(t & 31, t >> 5);
    M1 = mkmeta(t & 31, 8);
    __syncthreads();
}

__global__ __launch_bounds__(256, 4) void dcn_mfma(
    const float* __restrict__ x,
    const float* __restrict__ Wp,
    const float* __restrict__ bp,
    const float* __restrict__ Wc,
    float* __restrict__ out)
{
    __shared__ __align__(16) unsigned char smraw[36864];
    float* smf = (float*)smraw;
    unsigned short* bbuf = (unsigned short*)smraw;

    const int t  = threadIdx.x;
    const int bx = blockIdx.x;
    const int b  = bx >> 9;
    const int i  = (bx >> 2) & 127;
    const int j0 = (bx & 3) << 5;

    Meta M0, M1;
    offset_phase(x, Wp, bp, smf, b, i, j0, t, M0, M1);

    const int pos = t & 31;
    const int n0  = t >> 5;
    const int ccb = (t >> 5) << 2;
    const float* xb = x + b * (CC * HW);

    auto stage = [&](int ch0, int dbase) {
#pragma unroll 8
        for (int cc = 0; cc < 32; ++cc) {
            const float* p = xb + (ch0 + cc) * HW;
            float v = p[M0.i0] * M0.w0;
            v = fmaf(p[M0.i1], M0.w1, v);
            v = fmaf(p[M0.i2], M0.w2, v);
            v = fmaf(p[M0.i3], M0.w3, v);
            const int kp = cc * 9 + n0;
            bbuf[dbase + ((kp >> 3) << 8) + (pos << 3) + (kp & 7)] = bfbits(v);
        }
#pragma unroll
        for (int q = 0; q < 4; ++q) {
            const int cc = ccb + q;
            const float* p = xb + (ch0 + cc) * HW;
            float v = p[M1.i0] * M1.w0;
            v = fmaf(p[M1.i1], M1.w1, v);
            v = fmaf(p[M1.i2], M1.w2, v);
            v = fmaf(p[M1.i3], M1.w3, v);
            const int kp = cc * 9 + 8;
            bbuf[dbase + ((kp >> 3) << 8) + (pos << 3) + (kp & 7)] = bfbits(v);
        }
    };

    const int w_s = __builtin_amdgcn_readfirstlane(t >> 6);
    const int l   = t & 63;
    const int r   = l & 15;
    const int kb  = l >> 4;
    const float* arow = Wc + (w_s * 16 + r) * 576 + kb * 8;

    f32x4 acc0 = {0.f, 0.f, 0.f, 0.f};
    f32x4 acc1 = {0.f, 0.f, 0.f, 0.f};

    auto mfma_chunk = [&](int cb, int dbase) {
#pragma unroll 3
        for (int s = 0; s < 9; ++s) {
            const float* ap = arow + cb + s * 32;
            const float4 alo = *(const float4*)ap;
            const float4 ahi = *(const float4*)(ap + 4);
            bf16x8 af;
            af[0] = (short)bfbits(alo.x); af[1] = (short)bfbits(alo.y);
            af[2] = (short)bfbits(alo.z); af[3] = (short)bfbits(alo.w);
            af[4] = (short)bfbits(ahi.x); af[5] = (short)bfbits(ahi.y);
            af[6] = (short)bfbits(ahi.z); af[7] = (short)bfbits(ahi.w);
            const unsigned short* bp0 = bbuf + dbase + ((s * 4 + kb) << 8) + (r << 3);
            const bf16x8 bf0 = *(const bf16x8*)bp0;
            const bf16x8 bf1 = *(const bf16x8*)(bp0 + 128);
            acc0 = __builtin_amdgcn_mfma_f32_16x16x32_bf16(af, bf0, acc0, 0, 0, 0);
            acc1 = __builtin_amdgcn_mfma_f32_16x16x32_bf16(af, bf1, acc1, 0, 0, 0);
        }
    };

    stage(0, 0);
    __syncthreads();
    mfma_chunk(0, 0);
    stage(32, 9216);
    __syncthreads();
    mfma_chunk(288, 9216);

    const int ocb = b * OC + w_s * 16;
#pragma unroll
    for (int reg = 0; reg < 4; ++reg) {
        const int oc = ocb + (l >> 4) * 4 + reg;
        float* o = out + (oc * HH + i) * WW + j0;
        o[r]      = acc0[reg];
        o[16 + r] = acc1[reg];
    }
}

extern "C" void kernel_launch(void* const* d_in, const int* in_sizes, int n_in,
                              void* d_out, int out_size, void* d_ws, size_t ws_size,
                              hipStream_t stream) {
    const float* x  = (const float*)d_in[0];
    const float* Wp = (const float*)d_in[1];
    const float* bp = (const float*)d_in[2];
    const float* Wc = (const float*)d_in[3];
    float* out = (float*)d_out;
    if (ws_size >= (size_t)(OC * 576 * 2)) {
        unsigned short* Wb3 = (unsigned short*)d_ws;
        wpack2<<<dim3((OC * 576 + 255) / 256), dim3(256), 0, stream>>>(Wc, Wb3);
        dcn_wave<<<dim3(BB * HH * 4), dim3(256), 0, stream>>>(x, Wp, bp, Wb3, out);
    } else {
        dcn_mfma<<<dim3(BB * HH * 4), dim3(256), 0, stream>>>(x, Wp, bp, Wc, out);
    }
}

// Round 15
// 102.039 us; speedup vs baseline: 1.2286x; 1.2286x over previous
//
#include <hip/hip_runtime.h>
#include <hip/hip_bf16.h>

#define BB 2
#define CC 64
#define HH 128
#define WW 128
#define OC 64
#define HW (HH * WW)

typedef __attribute__((ext_vector_type(8))) short bf16x8;
typedef __attribute__((ext_vector_type(4))) float f32x4;

__device__ __forceinline__ unsigned short bfbits(float f) {
    __hip_bfloat16 h = __float2bfloat16(f);
    return __builtin_bit_cast(unsigned short, h);
}
__device__ __forceinline__ float frombits(unsigned short u) {
    unsigned int v = ((unsigned int)u) << 16;
    return __builtin_bit_cast(float, v);
}
__device__ __forceinline__ int iclamp(int v, int lo, int hi) {
    return v < lo ? lo : (v > hi ? hi : v);
}

// ws layout: [0,73728) Wb3 bf16 A-pack | [73728,663552) gmi short[2*9*16384]
//            [663552,3022848) gmw ushort4[2*9*16384]
#define WB3_BYTES   73728
#define GMI_OFF     73728
#define GMW_OFF     663552
#define WS_NEED     3022848

// ---------------- Wc -> bf16 A-fragment pack (R13-proven) ----------------
__global__ __launch_bounds__(256) void wpack2(const float* __restrict__ Wc,
                                              unsigned short* __restrict__ Wb3)
{
    const int idx = blockIdx.x * 256 + threadIdx.x;
    if (idx < OC * 576) {
        const int j = idx & 7;
        const int r = (idx >> 3) & 15;
        const int m = (idx >> 7) & 3;
        const int a = idx >> 9;
        const int n = a >> 3;
        const int c = (a & 7) * 8 + j;
        const int oc = m * 16 + r;
        Wb3[idx] = bfbits(Wc[oc * 576 + c * 9 + n]);
    }
}

// ---------------- kernel 1: offset conv + metadata -> global ----------------
__global__ __launch_bounds__(256, 2) void koffs(
    const float* __restrict__ x,
    const float* __restrict__ Wp,
    const float* __restrict__ bp,
    short* __restrict__ gmi,
    ushort4* __restrict__ gmw)
{
    __shared__ float part[4608];    // [8 grp][32 pos][18]
    const int t   = threadIdx.x;
    const int bxr = (blockIdx.x & 7) * 128 + (blockIdx.x >> 3);
    const int b   = bxr >> 9;
    const int i   = (bxr >> 2) & 127;
    const int j0  = (bxr & 3) << 5;

    {
        const int grp = t >> 5;
        const int pp  = t & 31;
        const int j   = j0 + pp;
        float acc[18];
#pragma unroll
        for (int o = 0; o < 18; ++o) acc[o] = 0.f;
        const float* xg = x + (b * CC + grp * 8) * HW;
        for (int c = 0; c < 8; ++c) {
            float xv[9];
#pragma unroll
            for (int dx = 0; dx < 3; ++dx) {
                const int ii = i + dx - 1;
                const bool okx = (unsigned)ii < (unsigned)HH;
#pragma unroll
                for (int dy = 0; dy < 3; ++dy) {
                    const int jj = j + dy - 1;
                    const bool ok = okx && ((unsigned)jj < (unsigned)WW);
                    xv[dx * 3 + dy] = ok ? xg[c * HW + ii * WW + jj] : 0.f;
                }
            }
            const float* wp = Wp + (grp * 8 + c) * 9;
#pragma unroll
            for (int o = 0; o < 18; ++o) {
                const float* w = wp + o * 576;
#pragma unroll
                for (int k = 0; k < 9; ++k)
                    acc[o] = fmaf(xv[k], w[k], acc[o]);
            }
        }
#pragma unroll
        for (int o = 0; o < 18; ++o)
            part[grp * 576 + pp * 18 + o] = acc[o];
    }
    __syncthreads();

    auto mkmeta = [&](int slot) {
        const int n   = slot >> 5;
        const int pos = slot & 31;
        const int kx  = n / 3, ky = n - kx * 3;
        float offx = bp[n], offy = bp[9 + n];
#pragma unroll
        for (int g = 0; g < 8; ++g) {
            offx += part[g * 576 + pos * 18 + n];
            offy += part[g * 576 + pos * 18 + 9 + n];
        }
        const float px = offx + (float)(kx - 1) + (float)(i + 1);
        const float py = offy + (float)(ky - 1) + (float)(j0 + pos + 1);
        const float flx = floorf(px), fly = floorf(py);
        const float qltx = fminf(fmaxf(flx,       0.f), 129.f);
        const float qlty = fminf(fmaxf(fly,       0.f), 129.f);
        const float qrbx = fminf(fmaxf(flx + 1.f, 0.f), 129.f);
        const float qrby = fminf(fmaxf(fly + 1.f, 0.f), 129.f);
        const float pxc  = fminf(fmaxf(px, 0.f), 129.f);
        const float pyc  = fminf(fmaxf(py, 0.f), 129.f);
        const float gx0 = 1.f + (qltx - pxc), gx1 = 1.f - (qrbx - pxc);
        const float gy0 = 1.f + (qlty - pyc), gy1 = 1.f - (qrby - pyc);
        const int rx0 = (int)qltx - 1, rx1 = (int)qrbx - 1;
        const int ry0 = (int)qlty - 1, ry1 = (int)qrby - 1;
        const bool vx0 = (unsigned)rx0 < (unsigned)HH, vx1 = (unsigned)rx1 < (unsigned)HH;
        const bool vy0 = (unsigned)ry0 < (unsigned)WW, vy1 = (unsigned)ry1 < (unsigned)WW;
        const float w0 = (vx0 && vy0) ? gx0 * gy0 : 0.f;   // +0
        const float w1 = (vx1 && vy1) ? gx1 * gy1 : 0.f;   // +129
        const float w2 = (vx0 && vy1) ? gx0 * gy1 : 0.f;   // +1
        const float w3 = (vx1 && vy0) ? gx1 * gy0 : 0.f;   // +128
        const int gidx = ((b * 9 + n) << 14) + (i << 7) + (j0 + pos);
        gmi[gidx] = (short)(rx0 * WW + ry0);
        gmw[gidx] = make_ushort4(bfbits(w0), bfbits(w1), bfbits(w2), bfbits(w3));
    };
    mkmeta(t);
    if (t < 32) mkmeta(256 + t);
}

// ---------------- kernel 2: gather + MFMA, barrier-free main loop -------------
// Block = 128 thr = 2 waves (K-halves) for one 16-pos strip, all 64 oc.
// Metadata read per step from global (L2-hot). LDS only for K-half reduce (4KB).
__global__ __launch_bounds__(128, 2) void kgemm(
    const float* __restrict__ x,
    const short* __restrict__ gmi,
    const ushort4* __restrict__ gmw,
    const unsigned short* __restrict__ Wb3,
    float* __restrict__ out)
{
    __shared__ __align__(16) float red[1024];   // 4 tiles x 64 lanes x 4

    const int t    = threadIdx.x;
    const int blk  = (blockIdx.x & 7) * 256 + (blockIdx.x >> 3);  // XCD swizzle
    const int b    = blk >> 10;
    const int strip = blk & 1023;
    const int i    = strip >> 3;
    const int j0   = (strip & 7) << 4;
    const int l    = t & 63;
    const int h    = t >> 6;          // K half
    const int r    = l & 15;
    const int kb   = l >> 4;
    const int pos  = j0 + r;
    const float* xb = x + b * (CC * HW);
    const unsigned short* wbase = Wb3 + (h * 36 + kb) * 512 + r * 8;

    f32x4 acc0 = {0.f, 0.f, 0.f, 0.f};
    f32x4 acc1 = {0.f, 0.f, 0.f, 0.f};
    f32x4 acc2 = {0.f, 0.f, 0.f, 0.f};
    f32x4 acc3 = {0.f, 0.f, 0.f, 0.f};

#pragma unroll 3
    for (int s = 0; s < 9; ++s) {
        const int a  = h * 36 + s * 4 + kb;     // k''-octet
        const int n  = a >> 3;
        const int c0 = (a & 7) * 8;
        const int gidx = ((b * 9 + n) << 14) + (i << 7) + pos;
        const int base = (int)gmi[gidx];
        const ushort4 wq = gmw[gidx];
        const float w0 = frombits(wq.x), w1 = frombits(wq.y);
        const float w2 = frombits(wq.z), w3 = frombits(wq.w);
        const int i0 = iclamp(base,       0, HW - 1);
        const int i1 = iclamp(base + 129, 0, HW - 1);
        const int i2 = iclamp(base + 1,   0, HW - 1);
        const int i3 = iclamp(base + 128, 0, HW - 1);
        const float* p = xb + c0 * HW;
        bf16x8 bfrag;
#pragma unroll
        for (int j = 0; j < 8; ++j) {
            float v = p[i0] * w0;
            v = fmaf(p[i1], w1, v);
            v = fmaf(p[i2], w2, v);
            v = fmaf(p[i3], w3, v);
            bfrag[j] = (short)bfbits(v);
            p += HW;
        }
        const unsigned short* wp8 = wbase + s * 2048;
        {
            const bf16x8 af0 = *(const bf16x8*)(wp8);
            const bf16x8 af1 = *(const bf16x8*)(wp8 + 128);
            acc0 = __builtin_amdgcn_mfma_f32_16x16x32_bf16(af0, bfrag, acc0, 0, 0, 0);
            acc1 = __builtin_amdgcn_mfma_f32_16x16x32_bf16(af1, bfrag, acc1, 0, 0, 0);
        }
        {
            const bf16x8 af2 = *(const bf16x8*)(wp8 + 256);
            const bf16x8 af3 = *(const bf16x8*)(wp8 + 384);
            acc2 = __builtin_amdgcn_mfma_f32_16x16x32_bf16(af2, bfrag, acc2, 0, 0, 0);
            acc3 = __builtin_amdgcn_mfma_f32_16x16x32_bf16(af3, bfrag, acc3, 0, 0, 0);
        }
    }

    if (h) {
        *(f32x4*)&red[0 * 256 + l * 4] = acc0;
        *(f32x4*)&red[1 * 256 + l * 4] = acc1;
        *(f32x4*)&red[2 * 256 + l * 4] = acc2;
        *(f32x4*)&red[3 * 256 + l * 4] = acc3;
    }
    __syncthreads();
    if (!h) {
        acc0 += *(const f32x4*)&red[0 * 256 + l * 4];
        acc1 += *(const f32x4*)&red[1 * 256 + l * 4];
        acc2 += *(const f32x4*)&red[2 * 256 + l * 4];
        acc3 += *(const f32x4*)&red[3 * 256 + l * 4];
        f32x4 av[4] = {acc0, acc1, acc2, acc3};
#pragma unroll
        for (int m = 0; m < 4; ++m)
#pragma unroll
            for (int reg = 0; reg < 4; ++reg) {
                const int oc = m * 16 + kb * 4 + reg;
                out[((b * OC + oc) * HH + i) * WW + pos] = av[m][reg];
            }
    }
}

// ---------------- fallback: R13 fused kernel (proven 98.9us) ----------------
__global__ __launch_bounds__(256, 2) void dcn_wave(
    const float* __restrict__ x,
    const float* __restrict__ Wp,
    const float* __restrict__ bp,
    const unsigned short* __restrict__ Wb3,
    float* __restrict__ out)
{
    __shared__ __align__(16) unsigned char smraw[21312];
    float*          part = (float*)smraw;
    short*          mi   = (short*)(smraw + 18432);
    ushort4*        mw   = (ushort4*)(smraw + 19008);

    const int t   = threadIdx.x;
    const int bxr = (blockIdx.x & 7) * 128 + (blockIdx.x >> 3);
    const int b   = bxr >> 9;
    const int i   = (bxr >> 2) & 127;
    const int j0  = (bxr & 3) << 5;

    {
        const int grp = t >> 5;
        const int pp  = t & 31;
        const int j   = j0 + pp;
        float acc[18];
#pragma unroll
        for (int o = 0; o < 18; ++o) acc[o] = 0.f;
        const float* xg = x + (b * CC + grp * 8) * HW;
        for (int c = 0; c < 8; ++c) {
            float xv[9];
#pragma unroll
            for (int dx = 0; dx < 3; ++dx) {
                const int ii = i + dx - 1;
                const bool okx = (unsigned)ii < (unsigned)HH;
#pragma unroll
                for (int dy = 0; dy < 3; ++dy) {
                    const int jj = j + dy - 1;
                    const bool ok = okx && ((unsigned)jj < (unsigned)WW);
                    xv[dx * 3 + dy] = ok ? xg[c * HW + ii * WW + jj] : 0.f;
                }
            }
            const float* wp = Wp + (grp * 8 + c) * 9;
#pragma unroll
            for (int o = 0; o < 18; ++o) {
                const float* w = wp + o * 576;
#pragma unroll
                for (int k = 0; k < 9; ++k)
                    acc[o] = fmaf(xv[k], w[k], acc[o]);
            }
        }
#pragma unroll
        for (int o = 0; o < 18; ++o)
            part[grp * 576 + pp * 18 + o] = acc[o];
    }
    __syncthreads();

    {
        auto mkmeta = [&](int slot) {
            const int n   = slot >> 5;
            const int pos = slot & 31;
            const int kx  = n / 3, ky = n - kx * 3;
            float offx = bp[n], offy = bp[9 + n];
#pragma unroll
            for (int g = 0; g < 8; ++g) {
                offx += part[g * 576 + pos * 18 + n];
                offy += part[g * 576 + pos * 18 + 9 + n];
            }
            const float px = offx + (float)(kx - 1) + (float)(i + 1);
            const float py = offy + (float)(ky - 1) + (float)(j0 + pos + 1);
            const float flx = floorf(px), fly = floorf(py);
            const float qltx = fminf(fmaxf(flx,       0.f), 129.f);
            const float qlty = fminf(fmaxf(fly,       0.f), 129.f);
            const float qrbx = fminf(fmaxf(flx + 1.f, 0.f), 129.f);
            const float qrby = fminf(fmaxf(fly + 1.f, 0.f), 129.f);
            const float pxc  = fminf(fmaxf(px, 0.f), 129.f);
            const float pyc  = fminf(fmaxf(py, 0.f), 129.f);
            const float gx0 = 1.f + (qltx - pxc), gx1 = 1.f - (qrbx - pxc);
            const float gy0 = 1.f + (qlty - pyc), gy1 = 1.f - (qrby - pyc);
            const int rx0 = (int)qltx - 1, rx1 = (int)qrbx - 1;
            const int ry0 = (int)qlty - 1, ry1 = (int)qrby - 1;
            const bool vx0 = (unsigned)rx0 < (unsigned)HH, vx1 = (unsigned)rx1 < (unsigned)HH;
            const bool vy0 = (unsigned)ry0 < (unsigned)WW, vy1 = (unsigned)ry1 < (unsigned)WW;
            const float w0 = (vx0 && vy0) ? gx0 * gy0 : 0.f;
            const float w1 = (vx1 && vy1) ? gx1 * gy1 : 0.f;
            const float w2 = (vx0 && vy1) ? gx0 * gy1 : 0.f;
            const float w3 = (vx1 && vy0) ? gx1 * gy0 : 0.f;
            mi[slot] = (short)(rx0 * WW + ry0);
            mw[slot] = make_ushort4(bfbits(w0), bfbits(w1), bfbits(w2), bfbits(w3));
        };
        mkmeta(t);
        if (t < 32) mkmeta(256 + t);
    }
    __syncthreads();

    const int l    = t & 63;
    const int w_   = t >> 6;
    const int sw   = w_ >> 1;
    const int half = w_ & 1;
    const int r    = l & 15;
    const int kb   = l >> 4;
    const int posl = sw * 16 + r;
    const float* xb = x + b * (CC * HW);
    const unsigned short* wbase = Wb3 + (half * 36 + kb) * 512 + r * 8;

    f32x4 acc0 = {0.f, 0.f, 0.f, 0.f};
    f32x4 acc1 = {0.f, 0.f, 0.f, 0.f};
    f32x4 acc2 = {0.f, 0.f, 0.f, 0.f};
    f32x4 acc3 = {0.f, 0.f, 0.f, 0.f};

#pragma unroll 3
    for (int s = 0; s < 9; ++s) {
        const int a  = half * 36 + s * 4 + kb;
        const int n  = a >> 3;
        const int c0 = (a & 7) * 8;
        const int slot = n * 32 + posl;
        const int base = (int)mi[slot];
        const ushort4 wq = mw[slot];
        const float w0 = frombits(wq.x), w1 = frombits(wq.y);
        const float w2 = frombits(wq.z), w3 = frombits(wq.w);
        const int i0 = iclamp(base,       0, HW - 1);
        const int i1 = iclamp(base + 129, 0, HW - 1);
        const int i2 = iclamp(base + 1,   0, HW - 1);
        const int i3 = iclamp(base + 128, 0, HW - 1);
        const float* p = xb + c0 * HW;
        bf16x8 bfrag;
#pragma unroll
        for (int j = 0; j < 8; ++j) {
            float v = p[i0] * w0;
            v = fmaf(p[i1], w1, v);
            v = fmaf(p[i2], w2, v);
            v = fmaf(p[i3], w3, v);
            bfrag[j] = (short)bfbits(v);
            p += HW;
        }
        const unsigned short* wp8 = wbase + s * 2048;
        const bf16x8 af0 = *(const bf16x8*)(wp8);
        const bf16x8 af1 = *(const bf16x8*)(wp8 + 128);
        const bf16x8 af2 = *(const bf16x8*)(wp8 + 256);
        const bf16x8 af3 = *(const bf16x8*)(wp8 + 384);
        acc0 = __builtin_amdgcn_mfma_f32_16x16x32_bf16(af0, bfrag, acc0, 0, 0, 0);
        acc1 = __builtin_amdgcn_mfma_f32_16x16x32_bf16(af1, bfrag, acc1, 0, 0, 0);
        acc2 = __builtin_amdgcn_mfma_f32_16x16x32_bf16(af2, bfrag, acc2, 0, 0, 0);
        acc3 = __builtin_amdgcn_mfma_f32_16x16x32_bf16(af3, bfrag, acc3, 0, 0, 0);
    }

    float* red = part;
    if (half) {
        *(f32x4*)&red[sw * 1024 + 0 * 256 + l * 4] = acc0;
        *(f32x4*)&red[sw * 1024 + 1 * 256 + l * 4] = acc1;
        *(f32x4*)&red[sw * 1024 + 2 * 256 + l * 4] = acc2;
        *(f32x4*)&red[sw * 1024 + 3 * 256 + l * 4] = acc3;
    }
    __syncthreads();
    if (!half) {
        acc0 += *(const f32x4*)&red[sw * 1024 + 0 * 256 + l * 4];
        acc1 += *(const f32x4*)&red[sw * 1024 + 1 * 256 + l * 4];
        acc2 += *(const f32x4*)&red[sw * 1024 + 2 * 256 + l * 4];
        acc3 += *(const f32x4*)&red[sw * 1024 + 3 * 256 + l * 4];
        const int jcol = j0 + posl;
        f32x4 av[4] = {acc0, acc1, acc2, acc3};
#pragma unroll
        for (int m = 0; m < 4; ++m)
#pragma unroll
            for (int reg = 0; reg < 4; ++reg) {
                const int oc = m * 16 + kb * 4 + reg;
                out[((b * OC + oc) * HH + i) * WW + jcol] = av[m][reg];
            }
    }
}

extern "C" void kernel_launch(void* const* d_in, const int* in_sizes, int n_in,
                              void* d_out, int out_size, void* d_ws, size_t ws_size,
                              hipStream_t stream) {
    const float* x  = (const float*)d_in[0];
    const float* Wp = (const float*)d_in[1];
    const float* bp = (const float*)d_in[2];
    const float* Wc = (const float*)d_in[3];
    float* out = (float*)d_out;
    unsigned char* ws = (unsigned char*)d_ws;
    unsigned short* Wb3 = (unsigned short*)ws;

    wpack2<<<dim3((OC * 576 + 255) / 256), dim3(256), 0, stream>>>(Wc, Wb3);
    if (ws_size >= (size_t)WS_NEED) {
        short*   gmi = (short*)(ws + GMI_OFF);
        ushort4* gmw = (ushort4*)(ws + GMW_OFF);
        koffs<<<dim3(BB * HH * 4), dim3(256), 0, stream>>>(x, Wp, bp, gmi, gmw);
        kgemm<<<dim3(BB * HH * 8), dim3(128), 0, stream>>>(x, gmi, gmw, Wb3, out);
    } else {
        dcn_wave<<<dim3(BB * HH * 4), dim3(256), 0, stream>>>(x, Wp, bp, Wb3, out);
    }
}

// Round 16
// 87.595 us; speedup vs baseline: 1.4312x; 1.1649x over previous
//
#include <hip/hip_runtime.h>
#include <hip/hip_bf16.h>

#define BB 2
#define CC 64
#define HH 128
#define WW 128
#define OC 64
#define HW (HH * WW)

typedef __attribute__((ext_vector_type(8))) short bf16x8;
typedef __attribute__((ext_vector_type(4))) float f32x4;

__device__ __forceinline__ unsigned short bfbits(float f) {
    __hip_bfloat16 h = __float2bfloat16(f);
    return __builtin_bit_cast(unsigned short, h);
}
__device__ __forceinline__ float frombits(unsigned short u) {
    unsigned int v = ((unsigned int)u) << 16;
    return __builtin_bit_cast(float, v);
}
__device__ __forceinline__ int iclamp(int v, int lo, int hi) {
    return v < lo ? lo : (v > hi ? hi : v);
}

// ws layout:
//  [0, 73728)            Wb3  bf16 A-fragment pack
//  [73728, 663552)       gmi  short[2*9*16384]
//  [663552, 3022848)     gmw  ushort4[2*9*16384]
//  [3022848, 11411456)   xT   float[2*16384*64]  (channels-last)
#define GMI_OFF     73728
#define GMW_OFF     663552
#define XT_OFF      3022848
#define WS_FULL     11411456

// ---------------- Wc -> bf16 A-fragment pack (R13-proven) ----------------
__global__ __launch_bounds__(256) void wpack2(const float* __restrict__ Wc,
                                              unsigned short* __restrict__ Wb3)
{
    const int idx = blockIdx.x * 256 + threadIdx.x;
    if (idx < OC * 576) {
        const int j = idx & 7;
        const int r = (idx >> 3) & 15;
        const int m = (idx >> 7) & 3;
        const int a = idx >> 9;
        const int n = a >> 3;
        const int c = (a & 7) * 8 + j;
        const int oc = m * 16 + r;
        Wb3[idx] = bfbits(Wc[oc * 576 + c * 9 + n]);
    }
}

// ---------------- x (NCHW) -> xT (NHWC) ----------------
__global__ __launch_bounds__(256) void xtrans(const float* __restrict__ x,
                                              float* __restrict__ xT)
{
    __shared__ float tile[64 * 65];
    const int t    = threadIdx.x;
    const int b    = blockIdx.x >> 8;
    const int pix0 = (blockIdx.x & 255) * 64;
#pragma unroll
    for (int it = 0; it < 4; ++it) {
        const int item = it * 256 + t;
        const int c  = item & 63;
        const int p4 = item >> 6;            // 0..15
        const float4 v = *(const float4*)&x[(b * 64 + c) * 16384 + pix0 + p4 * 4];
        tile[(p4 * 4 + 0) * 65 + c] = v.x;
        tile[(p4 * 4 + 1) * 65 + c] = v.y;
        tile[(p4 * 4 + 2) * 65 + c] = v.z;
        tile[(p4 * 4 + 3) * 65 + c] = v.w;
    }
    __syncthreads();
#pragma unroll
    for (int it = 0; it < 4; ++it) {
        const int item = it * 256 + t;
        const int p  = item & 63;
        const int c4 = item >> 6;            // 0..15
        float4 v;
        v.x = tile[p * 65 + c4 * 4 + 0];
        v.y = tile[p * 65 + c4 * 4 + 1];
        v.z = tile[p * 65 + c4 * 4 + 2];
        v.w = tile[p * 65 + c4 * 4 + 3];
        *(float4*)&xT[(b * 16384 + pix0 + p) * 64 + c4 * 4] = v;
    }
}

// ---------------- kernel 1: offset conv + metadata -> global (2048 blocks) ----
__global__ __launch_bounds__(256, 2) void koffs(
    const float* __restrict__ x,
    const float* __restrict__ Wp,
    const float* __restrict__ bp,
    short* __restrict__ gmi,
    ushort4* __restrict__ gmw)
{
    __shared__ float part[4608];    // [16 grp][16 pos][18]
    const int t  = threadIdx.x;
    const int bx = (blockIdx.x & 7) * 256 + (blockIdx.x >> 3);   // XCD swizzle
    const int b  = bx >> 10;
    const int i  = (bx >> 3) & 127;
    const int j0 = (bx & 7) << 4;

    {
        const int grp = t >> 4;          // 16 groups of 4 channels
        const int pp  = t & 15;
        const int j   = j0 + pp;
        float acc[18];
#pragma unroll
        for (int o = 0; o < 18; ++o) acc[o] = 0.f;
        const float* xg = x + (b * CC + grp * 4) * HW;
#pragma unroll 2
        for (int c = 0; c < 4; ++c) {
            float xv[9];
#pragma unroll
            for (int dx = 0; dx < 3; ++dx) {
                const int ii = i + dx - 1;
                const bool okx = (unsigned)ii < (unsigned)HH;
#pragma unroll
                for (int dy = 0; dy < 3; ++dy) {
                    const int jj = j + dy - 1;
                    const bool ok = okx && ((unsigned)jj < (unsigned)WW);
                    xv[dx * 3 + dy] = ok ? xg[c * HW + ii * WW + jj] : 0.f;
                }
            }
            const float* wp = Wp + (grp * 4 + c) * 9;
#pragma unroll
            for (int o = 0; o < 18; ++o) {
                const float* w = wp + o * 576;
#pragma unroll
                for (int k = 0; k < 9; ++k)
                    acc[o] = fmaf(xv[k], w[k], acc[o]);
            }
        }
#pragma unroll
        for (int o = 0; o < 18; ++o)
            part[grp * 288 + pp * 18 + o] = acc[o];
    }
    __syncthreads();

    if (t < 144) {
        const int n   = t >> 4;
        const int pos = t & 15;
        const int kx  = n / 3, ky = n - kx * 3;
        float offx = bp[n], offy = bp[9 + n];
#pragma unroll
        for (int g = 0; g < 16; ++g) {
            offx += part[g * 288 + pos * 18 + n];
            offy += part[g * 288 + pos * 18 + 9 + n];
        }
        const float px = offx + (float)(kx - 1) + (float)(i + 1);
        const float py = offy + (float)(ky - 1) + (float)(j0 + pos + 1);
        const float flx = floorf(px), fly = floorf(py);
        const float qltx = fminf(fmaxf(flx,       0.f), 129.f);
        const float qlty = fminf(fmaxf(fly,       0.f), 129.f);
        const float qrbx = fminf(fmaxf(flx + 1.f, 0.f), 129.f);
        const float qrby = fminf(fmaxf(fly + 1.f, 0.f), 129.f);
        const float pxc  = fminf(fmaxf(px, 0.f), 129.f);
        const float pyc  = fminf(fmaxf(py, 0.f), 129.f);
        const float gx0 = 1.f + (qltx - pxc), gx1 = 1.f - (qrbx - pxc);
        const float gy0 = 1.f + (qlty - pyc), gy1 = 1.f - (qrby - pyc);
        const int rx0 = (int)qltx - 1, rx1 = (int)qrbx - 1;
        const int ry0 = (int)qlty - 1, ry1 = (int)qrby - 1;
        const bool vx0 = (unsigned)rx0 < (unsigned)HH, vx1 = (unsigned)rx1 < (unsigned)HH;
        const bool vy0 = (unsigned)ry0 < (unsigned)WW, vy1 = (unsigned)ry1 < (unsigned)WW;
        const float w0 = (vx0 && vy0) ? gx0 * gy0 : 0.f;   // +0
        const float w1 = (vx1 && vy1) ? gx1 * gy1 : 0.f;   // +129
        const float w2 = (vx0 && vy1) ? gx0 * gy1 : 0.f;   // +1
        const float w3 = (vx1 && vy0) ? gx1 * gy0 : 0.f;   // +128
        const int gidx = ((b * 9 + n) << 14) + (i << 7) + (j0 + pos);
        gmi[gidx] = (short)(rx0 * WW + ry0);
        gmw[gidx] = make_ushort4(bfbits(w0), bfbits(w1), bfbits(w2), bfbits(w3));
    }
}

// ---------------- kernel 2: NHWC-coalesced gather + MFMA ----------------
// Block = 32-pos strip, 256 thr = 4 waves. Staging: lane = channel; per slot
// (pos,n): 4 wave-uniform-base coalesced 256B loads + broadcast metadata.
// XOR-swizzled LDS B-buf (write 32 banks x 2 = free). MFMA: wave = oc-tile,
// full K=576, 2 pos-tiles, no reduction.
__global__ __launch_bounds__(256, 2) void kgemm2(
    const float* __restrict__ xT,
    const short* __restrict__ gmi,
    const ushort4* __restrict__ gmw,
    const unsigned short* __restrict__ Wb3,
    float* __restrict__ out)
{
    __shared__ __align__(16) unsigned short bbuf[72 * 256];   // 36864 B

    const int t   = threadIdx.x;
    const int bxr = (blockIdx.x & 7) * 128 + (blockIdx.x >> 3);  // XCD swizzle
    const int b   = bxr >> 9;
    const int i   = (bxr >> 2) & 127;
    const int j0  = (bxr & 3) << 5;
    const int l   = t & 63;
    const int w   = t >> 6;

    // ---------------- staging: 72 slots per wave, lane = channel ----------------
    {
        const int c = l;
        const float* xb = xT + ((size_t)b << 14) * 64;
#pragma unroll 3
        for (int q = 0; q < 72; ++q) {
            const int slot = w * 72 + q;
            const int n   = slot >> 5;
            const int pos = slot & 31;
            const int gidx = ((b * 9 + n) << 14) + (i << 7) + (j0 + pos);
            const int base = (int)gmi[gidx];          // broadcast
            const ushort4 wq = gmw[gidx];             // broadcast
            const float w0 = frombits(wq.x), w1 = frombits(wq.y);
            const float w2 = frombits(wq.z), w3 = frombits(wq.w);
            const int i0 = iclamp(base,       0, HW - 1);
            const int i1 = iclamp(base + 129, 0, HW - 1);
            const int i2 = iclamp(base + 1,   0, HW - 1);
            const int i3 = iclamp(base + 128, 0, HW - 1);
            float v = xb[i0 * 64 + c] * w0;           // 256B coalesced each
            v = fmaf(xb[i1 * 64 + c], w1, v);
            v = fmaf(xb[i2 * 64 + c], w2, v);
            v = fmaf(xb[i3 * 64 + c], w3, v);
            // k'' = n*64 + c; row = n*8 + (c>>3); swizzled col = pos ^ (row&7)
            const int row = n * 8 + (c >> 3);
            const int pc  = pos ^ (row & 7);
            bbuf[row * 256 + pc * 8 + (c & 7)] = bfbits(v);
        }
    }
    __syncthreads();

    // ---------------- MFMA: wave = oc-tile, 18 steps, 2 pos-tiles --------------
    const int r  = l & 15;
    const int kb = l >> 4;
    const unsigned short* wbase = Wb3 + kb * 512 + w * 128 + r * 8;

    f32x4 acc0 = {0.f, 0.f, 0.f, 0.f};
    f32x4 acc1 = {0.f, 0.f, 0.f, 0.f};

#pragma unroll 3
    for (int s = 0; s < 18; ++s) {
        const int a = s * 4 + kb;
        const bf16x8 af = *(const bf16x8*)(wbase + s * 2048);
        const int pc0 = (r ^ (a & 7));              // pos-tile 0:  pos = r
        const bf16x8 bf0 = *(const bf16x8*)&bbuf[a * 256 + pc0 * 8];
        const bf16x8 bf1 = *(const bf16x8*)&bbuf[a * 256 + (16 + pc0) * 8]; // pos=16+r
        acc0 = __builtin_amdgcn_mfma_f32_16x16x32_bf16(af, bf0, acc0, 0, 0, 0);
        acc1 = __builtin_amdgcn_mfma_f32_16x16x32_bf16(af, bf1, acc1, 0, 0, 0);
    }

    // epilogue: col = lane&15 (pos in tile), row = kb*4 + reg (oc in tile)
#pragma unroll
    for (int reg = 0; reg < 4; ++reg) {
        const int oc = w * 16 + kb * 4 + reg;
        float* o = out + ((b * OC + oc) * HH + i) * WW + j0;
        o[r]      = acc0[reg];
        o[16 + r] = acc1[reg];
    }
}

// ---------------- fallback: R13 fused kernel (proven 98.9us) ----------------
__global__ __launch_bounds__(256, 2) void dcn_wave(
    const float* __restrict__ x,
    const float* __restrict__ Wp,
    const float* __restrict__ bp,
    const unsigned short* __restrict__ Wb3,
    float* __restrict__ out)
{
    __shared__ __align__(16) unsigned char smraw[21312];
    float*          part = (float*)smraw;
    short*          mi   = (short*)(smraw + 18432);
    ushort4*        mw   = (ushort4*)(smraw + 19008);

    const int t   = threadIdx.x;
    const int bxr = (blockIdx.x & 7) * 128 + (blockIdx.x >> 3);
    const int b   = bxr >> 9;
    const int i   = (bxr >> 2) & 127;
    const int j0  = (bxr & 3) << 5;

    {
        const int grp = t >> 5;
        const int pp  = t & 31;
        const int j   = j0 + pp;
        float acc[18];
#pragma unroll
        for (int o = 0; o < 18; ++o) acc[o] = 0.f;
        const float* xg = x + (b * CC + grp * 8) * HW;
        for (int c = 0; c < 8; ++c) {
            float xv[9];
#pragma unroll
            for (int dx = 0; dx < 3; ++dx) {
                const int ii = i + dx - 1;
                const bool okx = (unsigned)ii < (unsigned)HH;
#pragma unroll
                for (int dy = 0; dy < 3; ++dy) {
                    const int jj = j + dy - 1;
                    const bool ok = okx && ((unsigned)jj < (unsigned)WW);
                    xv[dx * 3 + dy] = ok ? xg[c * HW + ii * WW + jj] : 0.f;
                }
            }
            const float* wp = Wp + (grp * 8 + c) * 9;
#pragma unroll
            for (int o = 0; o < 18; ++o) {
                const float* w = wp + o * 576;
#pragma unroll
                for (int k = 0; k < 9; ++k)
                    acc[o] = fmaf(xv[k], w[k], acc[o]);
            }
        }
#pragma unroll
        for (int o = 0; o < 18; ++o)
            part[grp * 576 + pp * 18 + o] = acc[o];
    }
    __syncthreads();

    {
        auto mkmeta = [&](int slot) {
            const int n   = slot >> 5;
            const int pos = slot & 31;
            const int kx  = n / 3, ky = n - kx * 3;
            float offx = bp[n], offy = bp[9 + n];
#pragma unroll
            for (int g = 0; g < 8; ++g) {
                offx += part[g * 576 + pos * 18 + n];
                offy += part[g * 576 + pos * 18 + 9 + n];
            }
            const float px = offx + (float)(kx - 1) + (float)(i + 1);
            const float py = offy + (float)(ky - 1) + (float)(j0 + pos + 1);
            const float flx = floorf(px), fly = floorf(py);
            const float qltx = fminf(fmaxf(flx,       0.f), 129.f);
            const float qlty = fminf(fmaxf(fly,       0.f), 129.f);
            const float qrbx = fminf(fmaxf(flx + 1.f, 0.f), 129.f);
            const float qrby = fminf(fmaxf(fly + 1.f, 0.f), 129.f);
            const float pxc  = fminf(fmaxf(px, 0.f), 129.f);
            const float pyc  = fminf(fmaxf(py, 0.f), 129.f);
            const float gx0 = 1.f + (qltx - pxc), gx1 = 1.f - (qrbx - pxc);
            const float gy0 = 1.f + (qlty - pyc), gy1 = 1.f - (qrby - pyc);
            const int rx0 = (int)qltx - 1, rx1 = (int)qrbx - 1;
            const int ry0 = (int)qlty - 1, ry1 = (int)qrby - 1;
            const bool vx0 = (unsigned)rx0 < (unsigned)HH, vx1 = (unsigned)rx1 < (unsigned)HH;
            const bool vy0 = (unsigned)ry0 < (unsigned)WW, vy1 = (unsigned)ry1 < (unsigned)WW;
            const float w0 = (vx0 && vy0) ? gx0 * gy0 : 0.f;
            const float w1 = (vx1 && vy1) ? gx1 * gy1 : 0.f;
            const float w2 = (vx0 && vy1) ? gx0 * gy1 : 0.f;
            const float w3 = (vx1 && vy0) ? gx1 * gy0 : 0.f;
            mi[slot] = (short)(rx0 * WW + ry0);
            mw[slot] = make_ushort4(bfbits(w0), bfbits(w1), bfbits(w2), bfbits(w3));
        };
        mkmeta(t);
        if (t < 32) mkmeta(256 + t);
    }
    __syncthreads();

    const int l    = t & 63;
    const int w_   = t >> 6;
    const int sw   = w_ >> 1;
    const int half = w_ & 1;
    const int r    = l & 15;
    const int kb   = l >> 4;
    const int posl = sw * 16 + r;
    const float* xb = x + b * (CC * HW);
    const unsigned short* wbase = Wb3 + (half * 36 + kb) * 512 + r * 8;

    f32x4 acc0 = {0.f, 0.f, 0.f, 0.f};
    f32x4 acc1 = {0.f, 0.f, 0.f, 0.f};
    f32x4 acc2 = {0.f, 0.f, 0.f, 0.f};
    f32x4 acc3 = {0.f, 0.f, 0.f, 0.f};

#pragma unroll 3
    for (int s = 0; s < 9; ++s) {
        const int a  = half * 36 + s * 4 + kb;
        const int n  = a >> 3;
        const int c0 = (a & 7) * 8;
        const int slot = n * 32 + posl;
        const int base = (int)mi[slot];
        const ushort4 wq = mw[slot];
        const float w0 = frombits(wq.x), w1 = frombits(wq.y);
        const float w2 = frombits(wq.z), w3 = frombits(wq.w);
        const int i0 = iclamp(base,       0, HW - 1);
        const int i1 = iclamp(base + 129, 0, HW - 1);
        const int i2 = iclamp(base + 1,   0, HW - 1);
        const int i3 = iclamp(base + 128, 0, HW - 1);
        const float* p = xb + c0 * HW;
        bf16x8 bfrag;
#pragma unroll
        for (int j = 0; j < 8; ++j) {
            float v = p[i0] * w0;
            v = fmaf(p[i1], w1, v);
            v = fmaf(p[i2], w2, v);
            v = fmaf(p[i3], w3, v);
            bfrag[j] = (short)bfbits(v);
            p += HW;
        }
        const unsigned short* wp8 = wbase + s * 2048;
        const bf16x8 af0 = *(const bf16x8*)(wp8);
        const bf16x8 af1 = *(const bf16x8*)(wp8 + 128);
        const bf16x8 af2 = *(const bf16x8*)(wp8 + 256);
        const bf16x8 af3 = *(const bf16x8*)(wp8 + 384);
        acc0 = __builtin_amdgcn_mfma_f32_16x16x32_bf16(af0, bfrag, acc0, 0, 0, 0);
        acc1 = __builtin_amdgcn_mfma_f32_16x16x32_bf16(af1, bfrag, acc1, 0, 0, 0);
        acc2 = __builtin_amdgcn_mfma_f32_16x16x32_bf16(af2, bfrag, acc2, 0, 0, 0);
        acc3 = __builtin_amdgcn_mfma_f32_16x16x32_bf16(af3, bfrag, acc3, 0, 0, 0);
    }

    float* red = part;
    if (half) {
        *(f32x4*)&red[sw * 1024 + 0 * 256 + l * 4] = acc0;
        *(f32x4*)&red[sw * 1024 + 1 * 256 + l * 4] = acc1;
        *(f32x4*)&red[sw * 1024 + 2 * 256 + l * 4] = acc2;
        *(f32x4*)&red[sw * 1024 + 3 * 256 + l * 4] = acc3;
    }
    __syncthreads();
    if (!half) {
        acc0 += *(const f32x4*)&red[sw * 1024 + 0 * 256 + l * 4];
        acc1 += *(const f32x4*)&red[sw * 1024 + 1 * 256 + l * 4];
        acc2 += *(const f32x4*)&red[sw * 1024 + 2 * 256 + l * 4];
        acc3 += *(const f32x4*)&red[sw * 1024 + 3 * 256 + l * 4];
        const int jcol = j0 + posl;
        f32x4 av[4] = {acc0, acc1, acc2, acc3};
#pragma unroll
        for (int m = 0; m < 4; ++m)
#pragma unroll
            for (int reg = 0; reg < 4; ++reg) {
                const int oc = m * 16 + kb * 4 + reg;
                out[((b * OC + oc) * HH + i) * WW + jcol] = av[m][reg];
            }
    }
}

extern "C" void kernel_launch(void* const* d_in, const int* in_sizes, int n_in,
                              void* d_out, int out_size, void* d_ws, size_t ws_size,
                              hipStream_t stream) {
    const float* x  = (const float*)d_in[0];
    const float* Wp = (const float*)d_in[1];
    const float* bp = (const float*)d_in[2];
    const float* Wc = (const float*)d_in[3];
    float* out = (float*)d_out;
    unsigned char* ws = (unsigned char*)d_ws;
    unsigned short* Wb3 = (unsigned short*)ws;

    wpack2<<<dim3((OC * 576 + 255) / 256), dim3(256), 0, stream>>>(Wc, Wb3);
    if (ws_size >= (size_t)WS_FULL) {
        short*   gmi = (short*)(ws + GMI_OFF);
        ushort4* gmw = (ushort4*)(ws + GMW_OFF);
        float*   xT  = (float*)(ws + XT_OFF);
        xtrans<<<dim3(BB * 256), dim3(256), 0, stream>>>(x, xT);
        koffs<<<dim3(BB * HH * 8), dim3(256), 0, stream>>>(x, Wp, bp, gmi, gmw);
        kgemm2<<<dim3(BB * HH * 4), dim3(256), 0, stream>>>(xT, gmi, gmw, Wb3, out);
    } else {
        dcn_wave<<<dim3(BB * HH * 4), dim3(256), 0, stream>>>(x, Wp, bp, Wb3, out);
    }
}

// Round 17
// 68.821 us; speedup vs baseline: 1.8217x; 1.2728x over previous
//
#include <hip/hip_runtime.h>
#include <hip/hip_bf16.h>

#define BB 2
#define CC 64
#define HH 128
#define WW 128
#define OC 64
#define HW (HH * WW)

typedef __attribute__((ext_vector_type(8))) short bf16x8;
typedef __attribute__((ext_vector_type(4))) float f32x4;

__device__ __forceinline__ unsigned short bfbits(float f) {
    __hip_bfloat16 h = __float2bfloat16(f);
    return __builtin_bit_cast(unsigned short, h);
}
__device__ __forceinline__ float frombits(unsigned short u) {
    unsigned int v = ((unsigned int)u) << 16;
    return __builtin_bit_cast(float, v);
}
__device__ __forceinline__ int iclamp(int v, int lo, int hi) {
    return v < lo ? lo : (v > hi ? hi : v);
}

// ---- NEW ws layout (R17): Wb3 | wpk | gmi | gmw | xT ----
#define WPK_OFF2    73728
#define GMI_OFF2    110592
#define GMW_OFF2    700416
#define XT_OFF2     3059712
#define WS2_NEED    11448320
// ---- OLD ws layout (R16 mid-fallback) ----
#define GMI_OFF     73728
#define GMW_OFF     663552
#define XT_OFF      3022848
#define WS_FULL     11411456

// ---------------- Wc -> bf16 A-fragment pack (R13-proven) ----------------
__global__ __launch_bounds__(256) void wpack2(const float* __restrict__ Wc,
                                              unsigned short* __restrict__ Wb3)
{
    const int idx = blockIdx.x * 256 + threadIdx.x;
    if (idx < OC * 576) {
        const int j = idx & 7;
        const int r = (idx >> 3) & 15;
        const int m = (idx >> 7) & 3;
        const int a = idx >> 9;
        const int n = a >> 3;
        const int c = (a & 7) * 8 + j;
        const int oc = m * 16 + r;
        Wb3[idx] = bfbits(Wc[oc * 576 + c * 9 + n]);
    }
}

// ---------------- Wp -> bf16 A-fragment pack, M=32 (rows 18..31 zero) --------
// idx = a*256 + m*128 + r*8 + j ; a = k-octet (0..71), o = m*16+r, k''=a*8+j
__global__ __launch_bounds__(256) void wppack(const float* __restrict__ Wp,
                                              unsigned short* __restrict__ wpk)
{
    const int idx = blockIdx.x * 256 + threadIdx.x;
    if (idx < 32 * 576) {
        const int j = idx & 7;
        const int r = (idx >> 3) & 15;
        const int m = (idx >> 7) & 1;
        const int a = idx >> 8;
        const int n = a >> 3;
        const int c = (a & 7) * 8 + j;
        const int o = m * 16 + r;
        wpk[idx] = (o < 18) ? bfbits(Wp[o * 576 + c * 9 + n]) : (unsigned short)0;
    }
}

// ---------------- x (NCHW) -> xT (NHWC) ----------------
__global__ __launch_bounds__(256) void xtrans(const float* __restrict__ x,
                                              float* __restrict__ xT)
{
    __shared__ float tile[64 * 65];
    const int t    = threadIdx.x;
    const int b    = blockIdx.x >> 8;
    const int pix0 = (blockIdx.x & 255) * 64;
#pragma unroll
    for (int it = 0; it < 4; ++it) {
        const int item = it * 256 + t;
        const int c  = item & 63;
        const int p4 = item >> 6;
        const float4 v = *(const float4*)&x[(b * 64 + c) * 16384 + pix0 + p4 * 4];
        tile[(p4 * 4 + 0) * 65 + c] = v.x;
        tile[(p4 * 4 + 1) * 65 + c] = v.y;
        tile[(p4 * 4 + 2) * 65 + c] = v.z;
        tile[(p4 * 4 + 3) * 65 + c] = v.w;
    }
    __syncthreads();
#pragma unroll
    for (int it = 0; it < 4; ++it) {
        const int item = it * 256 + t;
        const int p  = item & 63;
        const int c4 = item >> 6;
        float4 v;
        v.x = tile[p * 65 + c4 * 4 + 0];
        v.y = tile[p * 65 + c4 * 4 + 1];
        v.z = tile[p * 65 + c4 * 4 + 2];
        v.w = tile[p * 65 + c4 * 4 + 3];
        *(float4*)&xT[(b * 16384 + pix0 + p) * 64 + c4 * 4] = v;
    }
}

// ---------------- kernel 1 (R17): MFMA offset conv + metadata ----------------
// Same machinery as kgemm2: 32-pos strip, NHWC-coalesced B staging (no bilinear,
// OOB->0), XOR-swizzled bbuf, 4 waves = 2 oc-tiles x 2 pos-tiles, K=576.
// Then 18x32 conv output -> LDS -> metadata math -> gmi/gmw.
__global__ __launch_bounds__(256, 2) void koffs2(
    const float* __restrict__ xT,
    const unsigned short* __restrict__ wpk,
    const float* __restrict__ bp,
    short* __restrict__ gmi,
    ushort4* __restrict__ gmw)
{
    __shared__ __align__(16) unsigned short bbuf[72 * 256];   // 36864 B
    __shared__ __align__(16) float odata[32 * 32];            // 4096 B

    const int t   = threadIdx.x;
    const int bxr = (blockIdx.x & 7) * 128 + (blockIdx.x >> 3);  // XCD swizzle
    const int b   = bxr >> 9;
    const int i   = (bxr >> 2) & 127;
    const int j0  = (bxr & 3) << 5;
    const int l   = t & 63;
    const int w   = t >> 6;

    // staging: 72 slots/wave, lane = channel; one coalesced 256B read per slot
    {
        const int c = l;
        const float* xb = xT + ((size_t)b << 14) * 64;
#pragma unroll 4
        for (int q = 0; q < 72; ++q) {
            const int slot = w * 72 + q;
            const int n   = slot >> 5;
            const int pos = slot & 31;
            const int kx = n / 3, ky = n - kx * 3;
            const int ii = i + kx - 1;
            const int jj = j0 + pos + ky - 1;
            const bool ok = ((unsigned)ii < (unsigned)HH) && ((unsigned)jj < (unsigned)WW);
            const float v = ok ? xb[(ii * WW + jj) * 64 + c] : 0.f;
            const int row = n * 8 + (c >> 3);
            const int pc  = pos ^ (row & 7);
            bbuf[row * 256 + pc * 8 + (c & 7)] = bfbits(v);
        }
    }
    __syncthreads();

    // MFMA: wave = (oc-tile, pos-tile); 18 steps, K=576
    {
        const int mt = w >> 1;
        const int pt = w & 1;
        const int r  = l & 15;
        const int kb = l >> 4;
        const unsigned short* wb = wpk + kb * 256 + mt * 128 + r * 8;
        f32x4 acc = {0.f, 0.f, 0.f, 0.f};
#pragma unroll 6
        for (int s = 0; s < 18; ++s) {
            const int a = s * 4 + kb;
            const bf16x8 af = *(const bf16x8*)(wb + s * 1024);
            const int pc = (pt * 16 + r) ^ (a & 7);
            const bf16x8 bf = *(const bf16x8*)&bbuf[a * 256 + pc * 8];
            acc = __builtin_amdgcn_mfma_f32_16x16x32_bf16(af, bf, acc, 0, 0, 0);
        }
#pragma unroll
        for (int reg = 0; reg < 4; ++reg)
            odata[(mt * 16 + kb * 4 + reg) * 32 + pt * 16 + r] = acc[reg];
    }
    __syncthreads();

    // metadata: slot = n*32 + pos (288 slots)
    {
        auto mkmeta = [&](int slot) {
            const int n   = slot >> 5;
            const int pos = slot & 31;
            const int kx  = n / 3, ky = n - kx * 3;
            const float offx = odata[n * 32 + pos] + bp[n];
            const float offy = odata[(9 + n) * 32 + pos] + bp[9 + n];
            const float px = offx + (float)(kx - 1) + (float)(i + 1);
            const float py = offy + (float)(ky - 1) + (float)(j0 + pos + 1);
            const float flx = floorf(px), fly = floorf(py);
            const float qltx = fminf(fmaxf(flx,       0.f), 129.f);
            const float qlty = fminf(fmaxf(fly,       0.f), 129.f);
            const float qrbx = fminf(fmaxf(flx + 1.f, 0.f), 129.f);
            const float qrby = fminf(fmaxf(fly + 1.f, 0.f), 129.f);
            const float pxc  = fminf(fmaxf(px, 0.f), 129.f);
            const float pyc  = fminf(fmaxf(py, 0.f), 129.f);
            const float gx0 = 1.f + (qltx - pxc), gx1 = 1.f - (qrbx - pxc);
            const float gy0 = 1.f + (qlty - pyc), gy1 = 1.f - (qrby - pyc);
            const int rx0 = (int)qltx - 1, rx1 = (int)qrbx - 1;
            const int ry0 = (int)qlty - 1, ry1 = (int)qrby - 1;
            const bool vx0 = (unsigned)rx0 < (unsigned)HH, vx1 = (unsigned)rx1 < (unsigned)HH;
            const bool vy0 = (unsigned)ry0 < (unsigned)WW, vy1 = (unsigned)ry1 < (unsigned)WW;
            const float w0 = (vx0 && vy0) ? gx0 * gy0 : 0.f;   // +0
            const float w1 = (vx1 && vy1) ? gx1 * gy1 : 0.f;   // +129
            const float w2 = (vx0 && vy1) ? gx0 * gy1 : 0.f;   // +1
            const float w3 = (vx1 && vy0) ? gx1 * gy0 : 0.f;   // +128
            const int gidx = ((b * 9 + n) << 14) + (i << 7) + (j0 + pos);
            gmi[gidx] = (short)(rx0 * WW + ry0);
            gmw[gidx] = make_ushort4(bfbits(w0), bfbits(w1), bfbits(w2), bfbits(w3));
        };
        mkmeta(t);
        if (t < 32) mkmeta(256 + t);
    }
}

// ---------------- kernel 1 (R16 mid-fallback): VALU offset conv --------------
__global__ __launch_bounds__(256, 2) void koffs(
    const float* __restrict__ x,
    const float* __restrict__ Wp,
    const float* __restrict__ bp,
    short* __restrict__ gmi,
    ushort4* __restrict__ gmw)
{
    __shared__ float part[4608];
    const int t  = threadIdx.x;
    const int bx = (blockIdx.x & 7) * 256 + (blockIdx.x >> 3);
    const int b  = bx >> 10;
    const int i  = (bx >> 3) & 127;
    const int j0 = (bx & 7) << 4;

    {
        const int grp = t >> 4;
        const int pp  = t & 15;
        const int j   = j0 + pp;
        float acc[18];
#pragma unroll
        for (int o = 0; o < 18; ++o) acc[o] = 0.f;
        const float* xg = x + (b * CC + grp * 4) * HW;
#pragma unroll 2
        for (int c = 0; c < 4; ++c) {
            float xv[9];
#pragma unroll
            for (int dx = 0; dx < 3; ++dx) {
                const int ii = i + dx - 1;
                const bool okx = (unsigned)ii < (unsigned)HH;
#pragma unroll
                for (int dy = 0; dy < 3; ++dy) {
                    const int jj = j + dy - 1;
                    const bool ok = okx && ((unsigned)jj < (unsigned)WW);
                    xv[dx * 3 + dy] = ok ? xg[c * HW + ii * WW + jj] : 0.f;
                }
            }
            const float* wp = Wp + (grp * 4 + c) * 9;
#pragma unroll
            for (int o = 0; o < 18; ++o) {
                const float* w = wp + o * 576;
#pragma unroll
                for (int k = 0; k < 9; ++k)
                    acc[o] = fmaf(xv[k], w[k], acc[o]);
            }
        }
#pragma unroll
        for (int o = 0; o < 18; ++o)
            part[grp * 288 + pp * 18 + o] = acc[o];
    }
    __syncthreads();

    if (t < 144) {
        const int n   = t >> 4;
        const int pos = t & 15;
        const int kx  = n / 3, ky = n - kx * 3;
        float offx = bp[n], offy = bp[9 + n];
#pragma unroll
        for (int g = 0; g < 16; ++g) {
            offx += part[g * 288 + pos * 18 + n];
            offy += part[g * 288 + pos * 18 + 9 + n];
        }
        const float px = offx + (float)(kx - 1) + (float)(i + 1);
        const float py = offy + (float)(ky - 1) + (float)(j0 + pos + 1);
        const float flx = floorf(px), fly = floorf(py);
        const float qltx = fminf(fmaxf(flx,       0.f), 129.f);
        const float qlty = fminf(fmaxf(fly,       0.f), 129.f);
        const float qrbx = fminf(fmaxf(flx + 1.f, 0.f), 129.f);
        const float qrby = fminf(fmaxf(fly + 1.f, 0.f), 129.f);
        const float pxc  = fminf(fmaxf(px, 0.f), 129.f);
        const float pyc  = fminf(fmaxf(py, 0.f), 129.f);
        const float gx0 = 1.f + (qltx - pxc), gx1 = 1.f - (qrbx - pxc);
        const float gy0 = 1.f + (qlty - pyc), gy1 = 1.f - (qrby - pyc);
        const int rx0 = (int)qltx - 1, rx1 = (int)qrbx - 1;
        const int ry0 = (int)qlty - 1, ry1 = (int)qrby - 1;
        const bool vx0 = (unsigned)rx0 < (unsigned)HH, vx1 = (unsigned)rx1 < (unsigned)HH;
        const bool vy0 = (unsigned)ry0 < (unsigned)WW, vy1 = (unsigned)ry1 < (unsigned)WW;
        const float w0 = (vx0 && vy0) ? gx0 * gy0 : 0.f;
        const float w1 = (vx1 && vy1) ? gx1 * gy1 : 0.f;
        const float w2 = (vx0 && vy1) ? gx0 * gy1 : 0.f;
        const float w3 = (vx1 && vy0) ? gx1 * gy0 : 0.f;
        const int gidx = ((b * 9 + n) << 14) + (i << 7) + (j0 + pos);
        gmi[gidx] = (short)(rx0 * WW + ry0);
        gmw[gidx] = make_ushort4(bfbits(w0), bfbits(w1), bfbits(w2), bfbits(w3));
    }
}

// ---------------- kernel 2: NHWC-coalesced gather + MFMA (R16-proven) --------
__global__ __launch_bounds__(256, 2) void kgemm2(
    const float* __restrict__ xT,
    const short* __restrict__ gmi,
    const ushort4* __restrict__ gmw,
    const unsigned short* __restrict__ Wb3,
    float* __restrict__ out)
{
    __shared__ __align__(16) unsigned short bbuf[72 * 256];

    const int t   = threadIdx.x;
    const int bxr = (blockIdx.x & 7) * 128 + (blockIdx.x >> 3);
    const int b   = bxr >> 9;
    const int i   = (bxr >> 2) & 127;
    const int j0  = (bxr & 3) << 5;
    const int l   = t & 63;
    const int w   = t >> 6;

    {
        const int c = l;
        const float* xb = xT + ((size_t)b << 14) * 64;
#pragma unroll 3
        for (int q = 0; q < 72; ++q) {
            const int slot = w * 72 + q;
            const int n   = slot >> 5;
            const int pos = slot & 31;
            const int gidx = ((b * 9 + n) << 14) + (i << 7) + (j0 + pos);
            const int base = (int)gmi[gidx];
            const ushort4 wq = gmw[gidx];
            const float w0 = frombits(wq.x), w1 = frombits(wq.y);
            const float w2 = frombits(wq.z), w3 = frombits(wq.w);
            const int i0 = iclamp(base,       0, HW - 1);
            const int i1 = iclamp(base + 129, 0, HW - 1);
            const int i2 = iclamp(base + 1,   0, HW - 1);
            const int i3 = iclamp(base + 128, 0, HW - 1);
            float v = xb[i0 * 64 + c] * w0;
            v = fmaf(xb[i1 * 64 + c], w1, v);
            v = fmaf(xb[i2 * 64 + c], w2, v);
            v = fmaf(xb[i3 * 64 + c], w3, v);
            const int row = n * 8 + (c >> 3);
            const int pc  = pos ^ (row & 7);
            bbuf[row * 256 + pc * 8 + (c & 7)] = bfbits(v);
        }
    }
    __syncthreads();

    const int r  = l & 15;
    const int kb = l >> 4;
    const unsigned short* wbase = Wb3 + kb * 512 + w * 128 + r * 8;

    f32x4 acc0 = {0.f, 0.f, 0.f, 0.f};
    f32x4 acc1 = {0.f, 0.f, 0.f, 0.f};

#pragma unroll 3
    for (int s = 0; s < 18; ++s) {
        const int a = s * 4 + kb;
        const bf16x8 af = *(const bf16x8*)(wbase + s * 2048);
        const int pc0 = (r ^ (a & 7));
        const bf16x8 bf0 = *(const bf16x8*)&bbuf[a * 256 + pc0 * 8];
        const bf16x8 bf1 = *(const bf16x8*)&bbuf[a * 256 + (16 + pc0) * 8];
        acc0 = __builtin_amdgcn_mfma_f32_16x16x32_bf16(af, bf0, acc0, 0, 0, 0);
        acc1 = __builtin_amdgcn_mfma_f32_16x16x32_bf16(af, bf1, acc1, 0, 0, 0);
    }

#pragma unroll
    for (int reg = 0; reg < 4; ++reg) {
        const int oc = w * 16 + kb * 4 + reg;
        float* o = out + ((b * OC + oc) * HH + i) * WW + j0;
        o[r]      = acc0[reg];
        o[16 + r] = acc1[reg];
    }
}

// ---------------- final fallback: R13 fused kernel (proven 98.9us) -----------
__global__ __launch_bounds__(256, 2) void dcn_wave(
    const float* __restrict__ x,
    const float* __restrict__ Wp,
    const float* __restrict__ bp,
    const unsigned short* __restrict__ Wb3,
    float* __restrict__ out)
{
    __shared__ __align__(16) unsigned char smraw[21312];
    float*          part = (float*)smraw;
    short*          mi   = (short*)(smraw + 18432);
    ushort4*        mw   = (ushort4*)(smraw + 19008);

    const int t   = threadIdx.x;
    const int bxr = (blockIdx.x & 7) * 128 + (blockIdx.x >> 3);
    const int b   = bxr >> 9;
    const int i   = (bxr >> 2) & 127;
    const int j0  = (bxr & 3) << 5;

    {
        const int grp = t >> 5;
        const int pp  = t & 31;
        const int j   = j0 + pp;
        float acc[18];
#pragma unroll
        for (int o = 0; o < 18; ++o) acc[o] = 0.f;
        const float* xg = x + (b * CC + grp * 8) * HW;
        for (int c = 0; c < 8; ++c) {
            float xv[9];
#pragma unroll
            for (int dx = 0; dx < 3; ++dx) {
                const int ii = i + dx - 1;
                const bool okx = (unsigned)ii < (unsigned)HH;
#pragma unroll
                for (int dy = 0; dy < 3; ++dy) {
                    const int jj = j + dy - 1;
                    const bool ok = okx && ((unsigned)jj < (unsigned)WW);
                    xv[dx * 3 + dy] = ok ? xg[c * HW + ii * WW + jj] : 0.f;
                }
            }
            const float* wp = Wp + (grp * 8 + c) * 9;
#pragma unroll
            for (int o = 0; o < 18; ++o) {
                const float* w = wp + o * 576;
#pragma unroll
                for (int k = 0; k < 9; ++k)
                    acc[o] = fmaf(xv[k], w[k], acc[o]);
            }
        }
#pragma unroll
        for (int o = 0; o < 18; ++o)
            part[grp * 576 + pp * 18 + o] = acc[o];
    }
    __syncthreads();

    {
        auto mkmeta = [&](int slot) {
            const int n   = slot >> 5;
            const int pos = slot & 31;
            const int kx  = n / 3, ky = n - kx * 3;
            float offx = bp[n], offy = bp[9 + n];
#pragma unroll
            for (int g = 0; g < 8; ++g) {
                offx += part[g * 576 + pos * 18 + n];
                offy += part[g * 576 + pos * 18 + 9 + n];
            }
            const float px = offx + (float)(kx - 1) + (float)(i + 1);
            const float py = offy + (float)(ky - 1) + (float)(j0 + pos + 1);
            const float flx = floorf(px), fly = floorf(py);
            const float qltx = fminf(fmaxf(flx,       0.f), 129.f);
            const float qlty = fminf(fmaxf(fly,       0.f), 129.f);
            const float qrbx = fminf(fmaxf(flx + 1.f, 0.f), 129.f);
            const float qrby = fminf(fmaxf(fly + 1.f, 0.f), 129.f);
            const float pxc  = fminf(fmaxf(px, 0.f), 129.f);
            const float pyc  = fminf(fmaxf(py, 0.f), 129.f);
            const float gx0 = 1.f + (qltx - pxc), gx1 = 1.f - (qrbx - pxc);
            const float gy0 = 1.f + (qlty - pyc), gy1 = 1.f - (qrby - pyc);
            const int rx0 = (int)qltx - 1, rx1 = (int)qrbx - 1;
            const int ry0 = (int)qlty - 1, ry1 = (int)qrby - 1;
            const bool vx0 = (unsigned)rx0 < (unsigned)HH, vx1 = (unsigned)rx1 < (unsigned)HH;
            const bool vy0 = (unsigned)ry0 < (unsigned)WW, vy1 = (unsigned)ry1 < (unsigned)WW;
            const float w0 = (vx0 && vy0) ? gx0 * gy0 : 0.f;
            const float w1 = (vx1 && vy1) ? gx1 * gy1 : 0.f;
            const float w2 = (vx0 && vy1) ? gx0 * gy1 : 0.f;
            const float w3 = (vx1 && vy0) ? gx1 * gy0 : 0.f;
            mi[slot] = (short)(rx0 * WW + ry0);
            mw[slot] = make_ushort4(bfbits(w0), bfbits(w1), bfbits(w2), bfbits(w3));
        };
        mkmeta(t);
        if (t < 32) mkmeta(256 + t);
    }
    __syncthreads();

    const int l    = t & 63;
    const int w_   = t >> 6;
    const int sw   = w_ >> 1;
    const int half = w_ & 1;
    const int r    = l & 15;
    const int kb   = l >> 4;
    const int posl = sw * 16 + r;
    const float* xb = x + b * (CC * HW);
    const unsigned short* wbase = Wb3 + (half * 36 + kb) * 512 + r * 8;

    f32x4 acc0 = {0.f, 0.f, 0.f, 0.f};
    f32x4 acc1 = {0.f, 0.f, 0.f, 0.f};
    f32x4 acc2 = {0.f, 0.f, 0.f, 0.f};
    f32x4 acc3 = {0.f, 0.f, 0.f, 0.f};

#pragma unroll 3
    for (int s = 0; s < 9; ++s) {
        const int a  = half * 36 + s * 4 + kb;
        const int n  = a >> 3;
        const int c0 = (a & 7) * 8;
        const int slot = n * 32 + posl;
        const int base = (int)mi[slot];
        const ushort4 wq = mw[slot];
        const float w0 = frombits(wq.x), w1 = frombits(wq.y);
        const float w2 = frombits(wq.z), w3 = frombits(wq.w);
        const int i0 = iclamp(base,       0, HW - 1);
        const int i1 = iclamp(base + 129, 0, HW - 1);
        const int i2 = iclamp(base + 1,   0, HW - 1);
        const int i3 = iclamp(base + 128, 0, HW - 1);
        const float* p = xb + c0 * HW;
        bf16x8 bfrag;
#pragma unroll
        for (int j = 0; j < 8; ++j) {
            float v = p[i0] * w0;
            v = fmaf(p[i1], w1, v);
            v = fmaf(p[i2], w2, v);
            v = fmaf(p[i3], w3, v);
            bfrag[j] = (short)bfbits(v);
            p += HW;
        }
        const unsigned short* wp8 = wbase + s * 2048;
        const bf16x8 af0 = *(const bf16x8*)(wp8);
        const bf16x8 af1 = *(const bf16x8*)(wp8 + 128);
        const bf16x8 af2 = *(const bf16x8*)(wp8 + 256);
        const bf16x8 af3 = *(const bf16x8*)(wp8 + 384);
        acc0 = __builtin_amdgcn_mfma_f32_16x16x32_bf16(af0, bfrag, acc0, 0, 0, 0);
        acc1 = __builtin_amdgcn_mfma_f32_16x16x32_bf16(af1, bfrag, acc1, 0, 0, 0);
        acc2 = __builtin_amdgcn_mfma_f32_16x16x32_bf16(af2, bfrag, acc2, 0, 0, 0);
        acc3 = __builtin_amdgcn_mfma_f32_16x16x32_bf16(af3, bfrag, acc3, 0, 0, 0);
    }

    float* red = part;
    if (half) {
        *(f32x4*)&red[sw * 1024 + 0 * 256 + l * 4] = acc0;
        *(f32x4*)&red[sw * 1024 + 1 * 256 + l * 4] = acc1;
        *(f32x4*)&red[sw * 1024 + 2 * 256 + l * 4] = acc2;
        *(f32x4*)&red[sw * 1024 + 3 * 256 + l * 4] = acc3;
    }
    __syncthreads();
    if (!half) {
        acc0 += *(const f32x4*)&red[sw * 1024 + 0 * 256 + l * 4];
        acc1 += *(const f32x4*)&red[sw * 1024 + 1 * 256 + l * 4];
        acc2 += *(const f32x4*)&red[sw * 1024 + 2 * 256 + l * 4];
        acc3 += *(const f32x4*)&red[sw * 1024 + 3 * 256 + l * 4];
        const int jcol = j0 + posl;
        f32x4 av[4] = {acc0, acc1, acc2, acc3};
#pragma unroll
        for (int m = 0; m < 4; ++m)
#pragma unroll
            for (int reg = 0; reg < 4; ++reg) {
                const int oc = m * 16 + kb * 4 + reg;
                out[((b * OC + oc) * HH + i) * WW + jcol] = av[m][reg];
            }
    }
}

extern "C" void kernel_launch(void* const* d_in, const int* in_sizes, int n_in,
                              void* d_out, int out_size, void* d_ws, size_t ws_size,
                              hipStream_t stream) {
    const float* x  = (const float*)d_in[0];
    const float* Wp = (const float*)d_in[1];
    const float* bp = (const float*)d_in[2];
    const float* Wc = (const float*)d_in[3];
    float* out = (float*)d_out;
    unsigned char* ws = (unsigned char*)d_ws;
    unsigned short* Wb3 = (unsigned short*)ws;

    wpack2<<<dim3((OC * 576 + 255) / 256), dim3(256), 0, stream>>>(Wc, Wb3);
    if (ws_size >= (size_t)WS2_NEED) {
        unsigned short* wpk = (unsigned short*)(ws + WPK_OFF2);
        short*   gmi = (short*)(ws + GMI_OFF2);
        ushort4* gmw = (ushort4*)(ws + GMW_OFF2);
        float*   xT  = (float*)(ws + XT_OFF2);
        wppack<<<dim3((32 * 576 + 255) / 256), dim3(256), 0, stream>>>(Wp, wpk);
        xtrans<<<dim3(BB * 256), dim3(256), 0, stream>>>(x, xT);
        koffs2<<<dim3(BB * HH * 4), dim3(256), 0, stream>>>(xT, wpk, bp, gmi, gmw);
        kgemm2<<<dim3(BB * HH * 4), dim3(256), 0, stream>>>(xT, gmi, gmw, Wb3, out);
    } else if (ws_size >= (size_t)WS_FULL) {
        short*   gmi = (short*)(ws + GMI_OFF);
        ushort4* gmw = (ushort4*)(ws + GMW_OFF);
        float*   xT  = (float*)(ws + XT_OFF);
        xtrans<<<dim3(BB * 256), dim3(256), 0, stream>>>(x, xT);
        koffs<<<dim3(BB * HH * 8), dim3(256), 0, stream>>>(x, Wp, bp, gmi, gmw);
        kgemm2<<<dim3(BB * HH * 4), dim3(256), 0, stream>>>(xT, gmi, gmw, Wb3, out);
    } else {
        dcn_wave<<<dim3(BB * HH * 4), dim3(256), 0, stream>>>(x, Wp, bp, Wb3, out);
    }
}

// Round 18
// 57.200 us; speedup vs baseline: 2.1918x; 1.2032x over previous
//
#include <hip/hip_runtime.h>
#include <hip/hip_bf16.h>

#define BB 2
#define CC 64
#define HH 128
#define WW 128
#define OC 64
#define HW (HH * WW)

typedef __attribute__((ext_vector_type(8))) short bf16x8;
typedef __attribute__((ext_vector_type(4))) float f32x4;

__device__ __forceinline__ unsigned short bfbits(float f) {
    __hip_bfloat16 h = __float2bfloat16(f);
    return __builtin_bit_cast(unsigned short, h);
}
__device__ __forceinline__ float frombits(unsigned short u) {
    unsigned int v = ((unsigned int)u) << 16;
    return __builtin_bit_cast(float, v);
}
__device__ __forceinline__ int iclamp(int v, int lo, int hi) {
    return v < lo ? lo : (v > hi ? hi : v);
}

// ws layout (R17): Wb3 | wpk | gmi | gmw | xT
#define WPK_OFF2    73728
#define GMI_OFF2    110592
#define GMW_OFF2    700416
#define XT_OFF2     3059712
#define WS2_NEED    11448320

// ---------------- fused prep: xtrans (blocks 0..511) + wpack2 (512..655)
//                  + wppack (656..727) ----------------
__global__ __launch_bounds__(256) void kprep(
    const float* __restrict__ x,
    const float* __restrict__ Wc,
    const float* __restrict__ Wp,
    float* __restrict__ xT,
    unsigned short* __restrict__ Wb3,
    unsigned short* __restrict__ wpk)
{
    __shared__ float tile[64 * 65];
    const int t  = threadIdx.x;
    const int bx = blockIdx.x;

    if (bx < 512) {                       // xtrans
        const int b    = bx >> 8;
        const int pix0 = (bx & 255) * 64;
#pragma unroll
        for (int it = 0; it < 4; ++it) {
            const int item = it * 256 + t;
            const int c  = item & 63;
            const int p4 = item >> 6;
            const float4 v = *(const float4*)&x[(b * 64 + c) * 16384 + pix0 + p4 * 4];
            tile[(p4 * 4 + 0) * 65 + c] = v.x;
            tile[(p4 * 4 + 1) * 65 + c] = v.y;
            tile[(p4 * 4 + 2) * 65 + c] = v.z;
            tile[(p4 * 4 + 3) * 65 + c] = v.w;
        }
        __syncthreads();
#pragma unroll
        for (int it = 0; it < 4; ++it) {
            const int item = it * 256 + t;
            const int p  = item & 63;
            const int c4 = item >> 6;
            float4 v;
            v.x = tile[p * 65 + c4 * 4 + 0];
            v.y = tile[p * 65 + c4 * 4 + 1];
            v.z = tile[p * 65 + c4 * 4 + 2];
            v.w = tile[p * 65 + c4 * 4 + 3];
            *(float4*)&xT[(b * 16384 + pix0 + p) * 64 + c4 * 4] = v;
        }
    } else if (bx < 656) {                // wpack2: Wc -> Wb3 A-fragment pack
        const int idx = (bx - 512) * 256 + t;
        if (idx < OC * 576) {
            const int j = idx & 7;
            const int r = (idx >> 3) & 15;
            const int m = (idx >> 7) & 3;
            const int a = idx >> 9;
            const int n = a >> 3;
            const int c = (a & 7) * 8 + j;
            const int oc = m * 16 + r;
            Wb3[idx] = bfbits(Wc[oc * 576 + c * 9 + n]);
        }
    } else {                              // wppack: Wp -> wpk (M=32, rows>=18 zero)
        const int idx = (bx - 656) * 256 + t;
        if (idx < 32 * 576) {
            const int j = idx & 7;
            const int r = (idx >> 3) & 15;
            const int m = (idx >> 7) & 1;
            const int a = idx >> 8;
            const int n = a >> 3;
            const int c = (a & 7) * 8 + j;
            const int o = m * 16 + r;
            wpk[idx] = (o < 18) ? bfbits(Wp[o * 576 + c * 9 + n]) : (unsigned short)0;
        }
    }
}

// ---------------- kernel 1: MFMA offset conv + metadata (R17-proven) ---------
__global__ __launch_bounds__(256, 2) void koffs2(
    const float* __restrict__ xT,
    const unsigned short* __restrict__ wpk,
    const float* __restrict__ bp,
    short* __restrict__ gmi,
    ushort4* __restrict__ gmw)
{
    __shared__ __align__(16) unsigned short bbuf[72 * 256];   // 36864 B
    __shared__ __align__(16) float odata[32 * 32];            // 4096 B

    const int t   = threadIdx.x;
    const int bxr = (blockIdx.x & 7) * 128 + (blockIdx.x >> 3);  // XCD swizzle
    const int b   = bxr >> 9;
    const int i   = (bxr >> 2) & 127;
    const int j0  = (bxr & 3) << 5;
    const int l   = t & 63;
    const int w   = t >> 6;

    // staging: 72 slots/wave, lane = channel; one coalesced 256B read per slot
    {
        const int c = l;
        const float* xb = xT + ((size_t)b << 14) * 64;
#pragma unroll 6
        for (int q = 0; q < 72; ++q) {
            const int slot = w * 72 + q;
            const int n   = slot >> 5;
            const int pos = slot & 31;
            const int kx = n / 3, ky = n - kx * 3;
            const int ii = i + kx - 1;
            const int jj = j0 + pos + ky - 1;
            const bool ok = ((unsigned)ii < (unsigned)HH) && ((unsigned)jj < (unsigned)WW);
            const float v = ok ? xb[(ii * WW + jj) * 64 + c] : 0.f;
            const int row = n * 8 + (c >> 3);
            const int pc  = pos ^ (row & 7);
            bbuf[row * 256 + pc * 8 + (c & 7)] = bfbits(v);
        }
    }
    __syncthreads();

    // MFMA: wave = (oc-tile, pos-tile); 18 steps, K=576
    {
        const int mt = w >> 1;
        const int pt = w & 1;
        const int r  = l & 15;
        const int kb = l >> 4;
        const unsigned short* wb = wpk + kb * 256 + mt * 128 + r * 8;
        f32x4 acc = {0.f, 0.f, 0.f, 0.f};
#pragma unroll 6
        for (int s = 0; s < 18; ++s) {
            const int a = s * 4 + kb;
            const bf16x8 af = *(const bf16x8*)(wb + s * 1024);
            const int pc = (pt * 16 + r) ^ (a & 7);
            const bf16x8 bf = *(const bf16x8*)&bbuf[a * 256 + pc * 8];
            acc = __builtin_amdgcn_mfma_f32_16x16x32_bf16(af, bf, acc, 0, 0, 0);
        }
#pragma unroll
        for (int reg = 0; reg < 4; ++reg)
            odata[(mt * 16 + kb * 4 + reg) * 32 + pt * 16 + r] = acc[reg];
    }
    __syncthreads();

    // metadata: slot = n*32 + pos (288 slots)
    {
        auto mkmeta = [&](int slot) {
            const int n   = slot >> 5;
            const int pos = slot & 31;
            const int kx  = n / 3, ky = n - kx * 3;
            const float offx = odata[n * 32 + pos] + bp[n];
            const float offy = odata[(9 + n) * 32 + pos] + bp[9 + n];
            const float px = offx + (float)(kx - 1) + (float)(i + 1);
            const float py = offy + (float)(ky - 1) + (float)(j0 + pos + 1);
            const float flx = floorf(px), fly = floorf(py);
            const float qltx = fminf(fmaxf(flx,       0.f), 129.f);
            const float qlty = fminf(fmaxf(fly,       0.f), 129.f);
            const float qrbx = fminf(fmaxf(flx + 1.f, 0.f), 129.f);
            const float qrby = fminf(fmaxf(fly + 1.f, 0.f), 129.f);
            const float pxc  = fminf(fmaxf(px, 0.f), 129.f);
            const float pyc  = fminf(fmaxf(py, 0.f), 129.f);
            const float gx0 = 1.f + (qltx - pxc), gx1 = 1.f - (qrbx - pxc);
            const float gy0 = 1.f + (qlty - pyc), gy1 = 1.f - (qrby - pyc);
            const int rx0 = (int)qltx - 1, rx1 = (int)qrbx - 1;
            const int ry0 = (int)qlty - 1, ry1 = (int)qrby - 1;
            const bool vx0 = (unsigned)rx0 < (unsigned)HH, vx1 = (unsigned)rx1 < (unsigned)HH;
            const bool vy0 = (unsigned)ry0 < (unsigned)WW, vy1 = (unsigned)ry1 < (unsigned)WW;
            const float w0 = (vx0 && vy0) ? gx0 * gy0 : 0.f;   // +0
            const float w1 = (vx1 && vy1) ? gx1 * gy1 : 0.f;   // +129
            const float w2 = (vx0 && vy1) ? gx0 * gy1 : 0.f;   // +1
            const float w3 = (vx1 && vy0) ? gx1 * gy0 : 0.f;   // +128
            const int gidx = ((b * 9 + n) << 14) + (i << 7) + (j0 + pos);
            gmi[gidx] = (short)(rx0 * WW + ry0);
            gmw[gidx] = make_ushort4(bfbits(w0), bfbits(w1), bfbits(w2), bfbits(w3));
        };
        mkmeta(t);
        if (t < 32) mkmeta(256 + t);
    }
}

// ---------------- kernel 2: NHWC gather + MFMA, meta prefetched to LDS -------
__global__ __launch_bounds__(256, 2) void kgemm2(
    const float* __restrict__ xT,
    const short* __restrict__ gmi,
    const ushort4* __restrict__ gmw,
    const unsigned short* __restrict__ Wb3,
    float* __restrict__ out)
{
    __shared__ __align__(16) unsigned short bbuf[72 * 256];   // 36864 B
    __shared__ short   smi[288];                              // 576 B
    __shared__ ushort4 smw[288];                              // 2304 B

    const int t   = threadIdx.x;
    const int bxr = (blockIdx.x & 7) * 128 + (blockIdx.x >> 3);  // XCD swizzle
    const int b   = bxr >> 9;
    const int i   = (bxr >> 2) & 127;
    const int j0  = (bxr & 3) << 5;
    const int l   = t & 63;
    const int w   = t >> 6;

    // phase 0: metadata prefetch (coalesced; breaks meta->gather latency chain)
    for (int slot = t; slot < 288; slot += 256) {
        const int n   = slot >> 5;
        const int pos = slot & 31;
        const int gidx = ((b * 9 + n) << 14) + (i << 7) + (j0 + pos);
        smi[slot] = gmi[gidx];
        smw[slot] = gmw[gidx];
    }
    __syncthreads();

    // staging: 72 slots per wave, lane = channel
    {
        const int c = l;
        const float* xb = xT + ((size_t)b << 14) * 64;
#pragma unroll 6
        for (int q = 0; q < 72; ++q) {
            const int slot = w * 72 + q;
            const int n   = slot >> 5;
            const int pos = slot & 31;
            const int base = (int)smi[slot];          // LDS broadcast
            const ushort4 wq = smw[slot];
            const float w0 = frombits(wq.x), w1 = frombits(wq.y);
            const float w2 = frombits(wq.z), w3 = frombits(wq.w);
            const int i0 = iclamp(base,       0, HW - 1);
            const int i1 = iclamp(base + 129, 0, HW - 1);
            const int i2 = iclamp(base + 1,   0, HW - 1);
            const int i3 = iclamp(base + 128, 0, HW - 1);
            float v = xb[i0 * 64 + c] * w0;           // 256B coalesced each
            v = fmaf(xb[i1 * 64 + c], w1, v);
            v = fmaf(xb[i2 * 64 + c], w2, v);
            v = fmaf(xb[i3 * 64 + c], w3, v);
            const int row = n * 8 + (c >> 3);
            const int pc  = pos ^ (row & 7);
            bbuf[row * 256 + pc * 8 + (c & 7)] = bfbits(v);
        }
    }
    __syncthreads();

    // MFMA: wave = oc-tile, 18 steps, 2 pos-tiles
    const int r  = l & 15;
    const int kb = l >> 4;
    const unsigned short* wbase = Wb3 + kb * 512 + w * 128 + r * 8;

    f32x4 acc0 = {0.f, 0.f, 0.f, 0.f};
    f32x4 acc1 = {0.f, 0.f, 0.f, 0.f};

#pragma unroll 3
    for (int s = 0; s < 18; ++s) {
        const int a = s * 4 + kb;
        const bf16x8 af = *(const bf16x8*)(wbase + s * 2048);
        const int pc0 = (r ^ (a & 7));
        const bf16x8 bf0 = *(const bf16x8*)&bbuf[a * 256 + pc0 * 8];
        const bf16x8 bf1 = *(const bf16x8*)&bbuf[a * 256 + (16 + pc0) * 8];
        acc0 = __builtin_amdgcn_mfma_f32_16x16x32_bf16(af, bf0, acc0, 0, 0, 0);
        acc1 = __builtin_amdgcn_mfma_f32_16x16x32_bf16(af, bf1, acc1, 0, 0, 0);
    }

#pragma unroll
    for (int reg = 0; reg < 4; ++reg) {
        const int oc = w * 16 + kb * 4 + reg;
        float* o = out + ((b * OC + oc) * HH + i) * WW + j0;
        o[r]      = acc0[reg];
        o[16 + r] = acc1[reg];
    }
}

// ---------------- final fallback: R13 fused kernel (proven 98.9us) -----------
__global__ __launch_bounds__(256) void wpack2fb(const float* __restrict__ Wc,
                                                unsigned short* __restrict__ Wb3)
{
    const int idx = blockIdx.x * 256 + threadIdx.x;
    if (idx < OC * 576) {
        const int j = idx & 7;
        const int r = (idx >> 3) & 15;
        const int m = (idx >> 7) & 3;
        const int a = idx >> 9;
        const int n = a >> 3;
        const int c = (a & 7) * 8 + j;
        const int oc = m * 16 + r;
        Wb3[idx] = bfbits(Wc[oc * 576 + c * 9 + n]);
    }
}

__global__ __launch_bounds__(256, 2) void dcn_wave(
    const float* __restrict__ x,
    const float* __restrict__ Wp,
    const float* __restrict__ bp,
    const unsigned short* __restrict__ Wb3,
    float* __restrict__ out)
{
    __shared__ __align__(16) unsigned char smraw[21312];
    float*          part = (float*)smraw;
    short*          mi   = (short*)(smraw + 18432);
    ushort4*        mw   = (ushort4*)(smraw + 19008);

    const int t   = threadIdx.x;
    const int bxr = (blockIdx.x & 7) * 128 + (blockIdx.x >> 3);
    const int b   = bxr >> 9;
    const int i   = (bxr >> 2) & 127;
    const int j0  = (bxr & 3) << 5;

    {
        const int grp = t >> 5;
        const int pp  = t & 31;
        const int j   = j0 + pp;
        float acc[18];
#pragma unroll
        for (int o = 0; o < 18; ++o) acc[o] = 0.f;
        const float* xg = x + (b * CC + grp * 8) * HW;
        for (int c = 0; c < 8; ++c) {
            float xv[9];
#pragma unroll
            for (int dx = 0; dx < 3; ++dx) {
                const int ii = i + dx - 1;
                const bool okx = (unsigned)ii < (unsigned)HH;
#pragma unroll
                for (int dy = 0; dy < 3; ++dy) {
                    const int jj = j + dy - 1;
                    const bool ok = okx && ((unsigned)jj < (unsigned)WW);
                    xv[dx * 3 + dy] = ok ? xg[c * HW + ii * WW + jj] : 0.f;
                }
            }
            const float* wp = Wp + (grp * 8 + c) * 9;
#pragma unroll
            for (int o = 0; o < 18; ++o) {
                const float* w = wp + o * 576;
#pragma unroll
                for (int k = 0; k < 9; ++k)
                    acc[o] = fmaf(xv[k], w[k], acc[o]);
            }
        }
#pragma unroll
        for (int o = 0; o < 18; ++o)
            part[grp * 576 + pp * 18 + o] = acc[o];
    }
    __syncthreads();

    {
        auto mkmeta = [&](int slot) {
            const int n   = slot >> 5;
            const int pos = slot & 31;
            const int kx  = n / 3, ky = n - kx * 3;
            float offx = bp[n], offy = bp[9 + n];
#pragma unroll
            for (int g = 0; g < 8; ++g) {
                offx += part[g * 576 + pos * 18 + n];
                offy += part[g * 576 + pos * 18 + 9 + n];
            }
            const float px = offx + (float)(kx - 1) + (float)(i + 1);
            const float py = offy + (float)(ky - 1) + (float)(j0 + pos + 1);
            const float flx = floorf(px), fly = floorf(py);
            const float qltx = fminf(fmaxf(flx,       0.f), 129.f);
            const float qlty = fminf(fmaxf(fly,       0.f), 129.f);
            const float qrbx = fminf(fmaxf(flx + 1.f, 0.f), 129.f);
            const float qrby = fminf(fmaxf(fly + 1.f, 0.f), 129.f);
            const float pxc  = fminf(fmaxf(px, 0.f), 129.f);
            const float pyc  = fminf(fmaxf(py, 0.f), 129.f);
            const float gx0 = 1.f + (qltx - pxc), gx1 = 1.f - (qrbx - pxc);
            const float gy0 = 1.f + (qlty - pyc), gy1 = 1.f - (qrby - pyc);
            const int rx0 = (int)qltx - 1, rx1 = (int)qrbx - 1;
            const int ry0 = (int)qlty - 1, ry1 = (int)qrby - 1;
            const bool vx0 = (unsigned)rx0 < (unsigned)HH, vx1 = (unsigned)rx1 < (unsigned)HH;
            const bool vy0 = (unsigned)ry0 < (unsigned)WW, vy1 = (unsigned)ry1 < (unsigned)WW;
            const float w0 = (vx0 && vy0) ? gx0 * gy0 : 0.f;
            const float w1 = (vx1 && vy1) ? gx1 * gy1 : 0.f;
            const float w2 = (vx0 && vy1) ? gx0 * gy1 : 0.f;
            const float w3 = (vx1 && vy0) ? gx1 * gy0 : 0.f;
            mi[slot] = (short)(rx0 * WW + ry0);
            mw[slot] = make_ushort4(bfbits(w0), bfbits(w1), bfbits(w2), bfbits(w3));
        };
        mkmeta(t);
        if (t < 32) mkmeta(256 + t);
    }
    __syncthreads();

    const int l    = t & 63;
    const int w_   = t >> 6;
    const int sw   = w_ >> 1;
    const int half = w_ & 1;
    const int r    = l & 15;
    const int kb   = l >> 4;
    const int posl = sw * 16 + r;
    const float* xb = x + b * (CC * HW);
    const unsigned short* wbase = Wb3 + (half * 36 + kb) * 512 + r * 8;

    f32x4 acc0 = {0.f, 0.f, 0.f, 0.f};
    f32x4 acc1 = {0.f, 0.f, 0.f, 0.f};
    f32x4 acc2 = {0.f, 0.f, 0.f, 0.f};
    f32x4 acc3 = {0.f, 0.f, 0.f, 0.f};

#pragma unroll 3
    for (int s = 0; s < 9; ++s) {
        const int a  = half * 36 + s * 4 + kb;
        const int n  = a >> 3;
        const int c0 = (a & 7) * 8;
        const int slot = n * 32 + posl;
        const int base = (int)mi[slot];
        const ushort4 wq = mw[slot];
        const float w0 = frombits(wq.x), w1 = frombits(wq.y);
        const float w2 = frombits(wq.z), w3 = frombits(wq.w);
        const int i0 = iclamp(base,       0, HW - 1);
        const int i1 = iclamp(base + 129, 0, HW - 1);
        const int i2 = iclamp(base + 1,   0, HW - 1);
        const int i3 = iclamp(base + 128, 0, HW - 1);
        const float* p = xb + c0 * HW;
        bf16x8 bfrag;
#pragma unroll
        for (int j = 0; j < 8; ++j) {
            float v = p[i0] * w0;
            v = fmaf(p[i1], w1, v);
            v = fmaf(p[i2], w2, v);
            v = fmaf(p[i3], w3, v);
            bfrag[j] = (short)bfbits(v);
            p += HW;
        }
        const unsigned short* wp8 = wbase + s * 2048;
        const bf16x8 af0 = *(const bf16x8*)(wp8);
        const bf16x8 af1 = *(const bf16x8*)(wp8 + 128);
        const bf16x8 af2 = *(const bf16x8*)(wp8 + 256);
        const bf16x8 af3 = *(const bf16x8*)(wp8 + 384);
        acc0 = __builtin_amdgcn_mfma_f32_16x16x32_bf16(af0, bfrag, acc0, 0, 0, 0);
        acc1 = __builtin_amdgcn_mfma_f32_16x16x32_bf16(af1, bfrag, acc1, 0, 0, 0);
        acc2 = __builtin_amdgcn_mfma_f32_16x16x32_bf16(af2, bfrag, acc2, 0, 0, 0);
        acc3 = __builtin_amdgcn_mfma_f32_16x16x32_bf16(af3, bfrag, acc3, 0, 0, 0);
    }

    float* red = part;
    if (half) {
        *(f32x4*)&red[sw * 1024 + 0 * 256 + l * 4] = acc0;
        *(f32x4*)&red[sw * 1024 + 1 * 256 + l * 4] = acc1;
        *(f32x4*)&red[sw * 1024 + 2 * 256 + l * 4] = acc2;
        *(f32x4*)&red[sw * 1024 + 3 * 256 + l * 4] = acc3;
    }
    __syncthreads();
    if (!half) {
        acc0 += *(const f32x4*)&red[sw * 1024 + 0 * 256 + l * 4];
        acc1 += *(const f32x4*)&red[sw * 1024 + 1 * 256 + l * 4];
        acc2 += *(const f32x4*)&red[sw * 1024 + 2 * 256 + l * 4];
        acc3 += *(const f32x4*)&red[sw * 1024 + 3 * 256 + l * 4];
        const int jcol = j0 + posl;
        f32x4 av[4] = {acc0, acc1, acc2, acc3};
#pragma unroll
        for (int m = 0; m < 4; ++m)
#pragma unroll
            for (int reg = 0; reg < 4; ++reg) {
                const int oc = m * 16 + kb * 4 + reg;
                out[((b * OC + oc) * HH + i) * WW + jcol] = av[m][reg];
            }
    }
}

extern "C" void kernel_launch(void* const* d_in, const int* in_sizes, int n_in,
                              void* d_out, int out_size, void* d_ws, size_t ws_size,
                              hipStream_t stream) {
    const float* x  = (const float*)d_in[0];
    const float* Wp = (const float*)d_in[1];
    const float* bp = (const float*)d_in[2];
    const float* Wc = (const float*)d_in[3];
    float* out = (float*)d_out;
    unsigned char* ws = (unsigned char*)d_ws;
    unsigned short* Wb3 = (unsigned short*)ws;

    if (ws_size >= (size_t)WS2_NEED) {
        unsigned short* wpk = (unsigned short*)(ws + WPK_OFF2);
        short*   gmi = (short*)(ws + GMI_OFF2);
        ushort4* gmw = (ushort4*)(ws + GMW_OFF2);
        float*   xT  = (float*)(ws + XT_OFF2);
        kprep<<<dim3(728), dim3(256), 0, stream>>>(x, Wc, Wp, xT, Wb3, wpk);
        koffs2<<<dim3(BB * HH * 4), dim3(256), 0, stream>>>(xT, wpk, bp, gmi, gmw);
        kgemm2<<<dim3(BB * HH * 4), dim3(256), 0, stream>>>(xT, gmi, gmw, Wb3, out);
    } else {
        wpack2fb<<<dim3((OC * 576 + 255) / 256), dim3(256), 0, stream>>>(Wc, Wb3);
        dcn_wave<<<dim3(BB * HH * 4), dim3(256), 0, stream>>>(x, Wp, bp, Wb3, out);
    }
}

// Round 19
// 46.770 us; speedup vs baseline: 2.6805x; 1.2230x over previous
//
#include <hip/hip_runtime.h>
#include <hip/hip_bf16.h>

#define BB 2
#define CC 64
#define HH 128
#define WW 128
#define OC 64
#define HW (HH * WW)

typedef __attribute__((ext_vector_type(8))) short bf16x8;
typedef __attribute__((ext_vector_type(4))) float f32x4;

__device__ __forceinline__ unsigned short bfbits(float f) {
    __hip_bfloat16 h = __float2bfloat16(f);
    return __builtin_bit_cast(unsigned short, h);
}
__device__ __forceinline__ float frombits(unsigned short u) {
    unsigned int v = ((unsigned int)u) << 16;
    return __builtin_bit_cast(float, v);
}
__device__ __forceinline__ int iclamp(int v, int lo, int hi) {
    return v < lo ? lo : (v > hi ? hi : v);
}

// ws layout (R19): Wb3 | wpk | xTb (bf16 NHWC)
#define WPK_OFF3    73728
#define XTB_OFF3    110592
#define WS3_NEED    4304896

// ---------------- fused prep: xtrans->bf16 (0..511) + wpack2 (512..655)
//                  + wppack (656..727) ----------------
__global__ __launch_bounds__(256) void kprep(
    const float* __restrict__ x,
    const float* __restrict__ Wc,
    const float* __restrict__ Wp,
    unsigned short* __restrict__ xTb,
    unsigned short* __restrict__ Wb3,
    unsigned short* __restrict__ wpk)
{
    __shared__ float tile[64 * 65];
    const int t  = threadIdx.x;
    const int bx = blockIdx.x;

    if (bx < 512) {                       // xtrans: NCHW f32 -> NHWC bf16
        const int b    = bx >> 8;
        const int pix0 = (bx & 255) * 64;
#pragma unroll
        for (int it = 0; it < 4; ++it) {
            const int item = it * 256 + t;
            const int c  = item & 63;
            const int p4 = item >> 6;
            const float4 v = *(const float4*)&x[(b * 64 + c) * 16384 + pix0 + p4 * 4];
            tile[(p4 * 4 + 0) * 65 + c] = v.x;
            tile[(p4 * 4 + 1) * 65 + c] = v.y;
            tile[(p4 * 4 + 2) * 65 + c] = v.z;
            tile[(p4 * 4 + 3) * 65 + c] = v.w;
        }
        __syncthreads();
#pragma unroll
        for (int it = 0; it < 4; ++it) {
            const int item = it * 256 + t;
            const int p  = item & 63;
            const int c4 = item >> 6;
            ushort4 v;
            v.x = bfbits(tile[p * 65 + c4 * 4 + 0]);
            v.y = bfbits(tile[p * 65 + c4 * 4 + 1]);
            v.z = bfbits(tile[p * 65 + c4 * 4 + 2]);
            v.w = bfbits(tile[p * 65 + c4 * 4 + 3]);
            *(ushort4*)&xTb[(b * 16384 + pix0 + p) * 64 + c4 * 4] = v;
        }
    } else if (bx < 656) {                // wpack2: Wc -> Wb3 A-fragment pack
        const int idx = (bx - 512) * 256 + t;
        if (idx < OC * 576) {
            const int j = idx & 7;
            const int r = (idx >> 3) & 15;
            const int m = (idx >> 7) & 3;
            const int a = idx >> 9;
            const int n = a >> 3;
            const int c = (a & 7) * 8 + j;
            const int oc = m * 16 + r;
            Wb3[idx] = bfbits(Wc[oc * 576 + c * 9 + n]);
        }
    } else {                              // wppack: Wp -> wpk (M=32, rows>=18 zero)
        const int idx = (bx - 656) * 256 + t;
        if (idx < 32 * 576) {
            const int j = idx & 7;
            const int r = (idx >> 3) & 15;
            const int m = (idx >> 7) & 1;
            const int a = idx >> 8;
            const int n = a >> 3;
            const int c = (a & 7) * 8 + j;
            const int o = m * 16 + r;
            wpk[idx] = (o < 18) ? bfbits(Wp[o * 576 + c * 9 + n]) : (unsigned short)0;
        }
    }
}

// ---------------- fused main: conv-MFMA -> metadata -> gather -> main-MFMA ---
// Block = 32-pos strip. 5 phases, 4 barriers, metadata stays in LDS.
// LDS 43.8KB -> 3 blocks/CU at (256,2) [VGPR cap = 256/min_waves, R2-R11].
__global__ __launch_bounds__(256, 2) void kmain(
    const unsigned short* __restrict__ xTb,
    const unsigned short* __restrict__ wpk,
    const unsigned short* __restrict__ Wb3,
    const float* __restrict__ bp,
    float* __restrict__ out)
{
    __shared__ __align__(16) unsigned short bbuf[72 * 256];   // 36864 B
    __shared__ __align__(16) float odata[32 * 32];            // 4096 B
    __shared__ short   smi[288];                              // 576 B
    __shared__ ushort4 smw[288];                              // 2304 B

    const int t   = threadIdx.x;
    const int bxr = (blockIdx.x & 7) * 128 + (blockIdx.x >> 3);  // XCD swizzle
    const int b   = bxr >> 9;
    const int i   = (bxr >> 2) & 127;
    const int j0  = (bxr & 3) << 5;
    const int l   = t & 63;
    const int w   = t >> 6;
    const int sh  = l >> 5;            // slot half (0/1) for pair-staging
    const int c0  = (l & 31) * 2;      // channel pair base
    const unsigned short* xb = xTb + (((size_t)b) << 14) * 64;

    // ---- phase 1: patch staging (pure bf16 copy, 2 slots/iter) ----
#pragma unroll 6
    for (int q = 0; q < 36; ++q) {
        const int slot = w * 72 + q * 2 + sh;
        const int n   = slot >> 5;
        const int pos = slot & 31;
        const int kx = n / 3, ky = n - kx * 3;
        const int ii = i + kx - 1;
        const int jj = j0 + pos + ky - 1;
        const bool ok = ((unsigned)ii < (unsigned)HH) && ((unsigned)jj < (unsigned)WW);
        unsigned int v = 0;
        if (ok) v = *(const unsigned int*)&xb[(ii * WW + jj) * 64 + c0];
        const int row = n * 8 + (c0 >> 3);
        const int pc  = pos ^ (row & 7);
        *(unsigned int*)((char*)bbuf + row * 512 + pc * 16 + (c0 & 7) * 2) = v;
    }
    __syncthreads();

    // ---- phase 2: offset-conv MFMA (wave = oc-tile x pos-tile, K=576) ----
    {
        const int mt = w >> 1;
        const int pt = w & 1;
        const int r  = l & 15;
        const int kb = l >> 4;
        const unsigned short* wb = wpk + kb * 256 + mt * 128 + r * 8;
        f32x4 acc = {0.f, 0.f, 0.f, 0.f};
#pragma unroll 6
        for (int s = 0; s < 18; ++s) {
            const int a = s * 4 + kb;
            const bf16x8 af = *(const bf16x8*)(wb + s * 1024);
            const int pc = (pt * 16 + r) ^ (a & 7);
            const bf16x8 bf = *(const bf16x8*)&bbuf[a * 256 + pc * 8];
            acc = __builtin_amdgcn_mfma_f32_16x16x32_bf16(af, bf, acc, 0, 0, 0);
        }
#pragma unroll
        for (int reg = 0; reg < 4; ++reg)
            odata[(mt * 16 + kb * 4 + reg) * 32 + pt * 16 + r] = acc[reg];
    }
    __syncthreads();

    // ---- phase 3: metadata (288 slots) -> LDS ----
    {
        auto mkmeta = [&](int slot) {
            const int n   = slot >> 5;
            const int pos = slot & 31;
            const int kx  = n / 3, ky = n - kx * 3;
            const float offx = odata[n * 32 + pos] + bp[n];
            const float offy = odata[(9 + n) * 32 + pos] + bp[9 + n];
            const float px = offx + (float)(kx - 1) + (float)(i + 1);
            const float py = offy + (float)(ky - 1) + (float)(j0 + pos + 1);
            const float flx = floorf(px), fly = floorf(py);
            const float qltx = fminf(fmaxf(flx,       0.f), 129.f);
            const float qlty = fminf(fmaxf(fly,       0.f), 129.f);
            const float qrbx = fminf(fmaxf(flx + 1.f, 0.f), 129.f);
            const float qrby = fminf(fmaxf(fly + 1.f, 0.f), 129.f);
            const float pxc  = fminf(fmaxf(px, 0.f), 129.f);
            const float pyc  = fminf(fmaxf(py, 0.f), 129.f);
            const float gx0 = 1.f + (qltx - pxc), gx1 = 1.f - (qrbx - pxc);
            const float gy0 = 1.f + (qlty - pyc), gy1 = 1.f - (qrby - pyc);
            const int rx0 = (int)qltx - 1, rx1 = (int)qrbx - 1;
            const int ry0 = (int)qlty - 1, ry1 = (int)qrby - 1;
            const bool vx0 = (unsigned)rx0 < (unsigned)HH, vx1 = (unsigned)rx1 < (unsigned)HH;
            const bool vy0 = (unsigned)ry0 < (unsigned)WW, vy1 = (unsigned)ry1 < (unsigned)WW;
            const float w0 = (vx0 && vy0) ? gx0 * gy0 : 0.f;   // +0
            const float w1 = (vx1 && vy1) ? gx1 * gy1 : 0.f;   // +129
            const float w2 = (vx0 && vy1) ? gx0 * gy1 : 0.f;   // +1
            const float w3 = (vx1 && vy0) ? gx1 * gy0 : 0.f;   // +128
            smi[slot] = (short)(rx0 * WW + ry0);
            smw[slot] = make_ushort4(bfbits(w0), bfbits(w1), bfbits(w2), bfbits(w3));
        };
        mkmeta(t);
        if (t < 32) mkmeta(256 + t);
    }
    __syncthreads();

    // ---- phase 4: bilinear staging (bf16 corners, 2 slots/iter) ----
#pragma unroll 6
    for (int q = 0; q < 36; ++q) {
        const int slot = w * 72 + q * 2 + sh;
        const int n   = slot >> 5;
        const int pos = slot & 31;
        const int base = (int)smi[slot];
        const ushort4 wq = smw[slot];
        const float w0 = frombits(wq.x), w1 = frombits(wq.y);
        const float w2 = frombits(wq.z), w3 = frombits(wq.w);
        const int i0 = iclamp(base,       0, HW - 1);
        const int i1 = iclamp(base + 129, 0, HW - 1);
        const int i2 = iclamp(base + 1,   0, HW - 1);
        const int i3 = iclamp(base + 128, 0, HW - 1);
        const unsigned int u0 = *(const unsigned int*)&xb[i0 * 64 + c0];
        const unsigned int u1 = *(const unsigned int*)&xb[i1 * 64 + c0];
        const unsigned int u2 = *(const unsigned int*)&xb[i2 * 64 + c0];
        const unsigned int u3 = *(const unsigned int*)&xb[i3 * 64 + c0];
        float vlo = frombits((unsigned short)u0) * w0;
        vlo = fmaf(frombits((unsigned short)u1), w1, vlo);
        vlo = fmaf(frombits((unsigned short)u2), w2, vlo);
        vlo = fmaf(frombits((unsigned short)u3), w3, vlo);
        float vhi = frombits((unsigned short)(u0 >> 16)) * w0;
        vhi = fmaf(frombits((unsigned short)(u1 >> 16)), w1, vhi);
        vhi = fmaf(frombits((unsigned short)(u2 >> 16)), w2, vhi);
        vhi = fmaf(frombits((unsigned short)(u3 >> 16)), w3, vhi);
        const unsigned int vv = (unsigned int)bfbits(vlo)
                              | ((unsigned int)bfbits(vhi) << 16);
        const int row = n * 8 + (c0 >> 3);
        const int pc  = pos ^ (row & 7);
        *(unsigned int*)((char*)bbuf + row * 512 + pc * 16 + (c0 & 7) * 2) = vv;
    }
    __syncthreads();

    // ---- phase 5: main MFMA (wave = oc-tile, 18 steps, 2 pos-tiles) ----
    {
        const int r  = l & 15;
        const int kb = l >> 4;
        const unsigned short* wbase = Wb3 + kb * 512 + w * 128 + r * 8;
        f32x4 acc0 = {0.f, 0.f, 0.f, 0.f};
        f32x4 acc1 = {0.f, 0.f, 0.f, 0.f};
#pragma unroll 3
        for (int s = 0; s < 18; ++s) {
            const int a = s * 4 + kb;
            const bf16x8 af = *(const bf16x8*)(wbase + s * 2048);
            const int pc0 = (r ^ (a & 7));
            const bf16x8 bf0 = *(const bf16x8*)&bbuf[a * 256 + pc0 * 8];
            const bf16x8 bf1 = *(const bf16x8*)&bbuf[a * 256 + (16 + pc0) * 8];
            acc0 = __builtin_amdgcn_mfma_f32_16x16x32_bf16(af, bf0, acc0, 0, 0, 0);
            acc1 = __builtin_amdgcn_mfma_f32_16x16x32_bf16(af, bf1, acc1, 0, 0, 0);
        }
#pragma unroll
        for (int reg = 0; reg < 4; ++reg) {
            const int oc = w * 16 + kb * 4 + reg;
            float* o = out + ((b * OC + oc) * HH + i) * WW + j0;
            o[r]      = acc0[reg];
            o[16 + r] = acc1[reg];
        }
    }
}

// ---------------- fallback: R13 fused kernel (proven 98.9us) ----------------
__global__ __launch_bounds__(256) void wpack2fb(const float* __restrict__ Wc,
                                                unsigned short* __restrict__ Wb3)
{
    const int idx = blockIdx.x * 256 + threadIdx.x;
    if (idx < OC * 576) {
        const int j = idx & 7;
        const int r = (idx >> 3) & 15;
        const int m = (idx >> 7) & 3;
        const int a = idx >> 9;
        const int n = a >> 3;
        const int c = (a & 7) * 8 + j;
        const int oc = m * 16 + r;
        Wb3[idx] = bfbits(Wc[oc * 576 + c * 9 + n]);
    }
}

__global__ __launch_bounds__(256, 2) void dcn_wave(
    const float* __restrict__ x,
    const float* __restrict__ Wp,
    const float* __restrict__ bp,
    const unsigned short* __restrict__ Wb3,
    float* __restrict__ out)
{
    __shared__ __align__(16) unsigned char smraw[21312];
    float*          part = (float*)smraw;
    short*          mi   = (short*)(smraw + 18432);
    ushort4*        mw   = (ushort4*)(smraw + 19008);

    const int t   = threadIdx.x;
    const int bxr = (blockIdx.x & 7) * 128 + (blockIdx.x >> 3);
    const int b   = bxr >> 9;
    const int i   = (bxr >> 2) & 127;
    const int j0  = (bxr & 3) << 5;

    {
        const int grp = t >> 5;
        const int pp  = t & 31;
        const int j   = j0 + pp;
        float acc[18];
#pragma unroll
        for (int o = 0; o < 18; ++o) acc[o] = 0.f;
        const float* xg = x + (b * CC + grp * 8) * HW;
        for (int c = 0; c < 8; ++c) {
            float xv[9];
#pragma unroll
            for (int dx = 0; dx < 3; ++dx) {
                const int ii = i + dx - 1;
                const bool okx = (unsigned)ii < (unsigned)HH;
#pragma unroll
                for (int dy = 0; dy < 3; ++dy) {
                    const int jj = j + dy - 1;
                    const bool ok = okx && ((unsigned)jj < (unsigned)WW);
                    xv[dx * 3 + dy] = ok ? xg[c * HW + ii * WW + jj] : 0.f;
                }
            }
            const float* wp = Wp + (grp * 8 + c) * 9;
#pragma unroll
            for (int o = 0; o < 18; ++o) {
                const float* w = wp + o * 576;
#pragma unroll
                for (int k = 0; k < 9; ++k)
                    acc[o] = fmaf(xv[k], w[k], acc[o]);
            }
        }
#pragma unroll
        for (int o = 0; o < 18; ++o)
            part[grp * 576 + pp * 18 + o] = acc[o];
    }
    __syncthreads();

    {
        auto mkmeta = [&](int slot) {
            const int n   = slot >> 5;
            const int pos = slot & 31;
            const int kx  = n / 3, ky = n - kx * 3;
            float offx = bp[n], offy = bp[9 + n];
#pragma unroll
            for (int g = 0; g < 8; ++g) {
                offx += part[g * 576 + pos * 18 + n];
                offy += part[g * 576 + pos * 18 + 9 + n];
            }
            const float px = offx + (float)(kx - 1) + (float)(i + 1);
            const float py = offy + (float)(ky - 1) + (float)(j0 + pos + 1);
            const float flx = floorf(px), fly = floorf(py);
            const float qltx = fminf(fmaxf(flx,       0.f), 129.f);
            const float qlty = fminf(fmaxf(fly,       0.f), 129.f);
            const float qrbx = fminf(fmaxf(flx + 1.f, 0.f), 129.f);
            const float qrby = fminf(fmaxf(fly + 1.f, 0.f), 129.f);
            const float pxc  = fminf(fmaxf(px, 0.f), 129.f);
            const float pyc  = fminf(fmaxf(py, 0.f), 129.f);
            const float gx0 = 1.f + (qltx - pxc), gx1 = 1.f - (qrbx - pxc);
            const float gy0 = 1.f + (qlty - pyc), gy1 = 1.f - (qrby - pyc);
            const int rx0 = (int)qltx - 1, rx1 = (int)qrbx - 1;
            const int ry0 = (int)qlty - 1, ry1 = (int)qrby - 1;
            const bool vx0 = (unsigned)rx0 < (unsigned)HH, vx1 = (unsigned)rx1 < (unsigned)HH;
            const bool vy0 = (unsigned)ry0 < (unsigned)WW, vy1 = (unsigned)ry1 < (unsigned)WW;
            const float w0 = (vx0 && vy0) ? gx0 * gy0 : 0.f;
            const float w1 = (vx1 && vy1) ? gx1 * gy1 : 0.f;
            const float w2 = (vx0 && vy1) ? gx0 * gy1 : 0.f;
            const float w3 = (vx1 && vy0) ? gx1 * gy0 : 0.f;
            mi[slot] = (short)(rx0 * WW + ry0);
            mw[slot] = make_ushort4(bfbits(w0), bfbits(w1), bfbits(w2), bfbits(w3));
        };
        mkmeta(t);
        if (t < 32) mkmeta(256 + t);
    }
    __syncthreads();

    const int l    = t & 63;
    const int w_   = t >> 6;
    const int sw   = w_ >> 1;
    const int half = w_ & 1;
    const int r    = l & 15;
    const int kb   = l >> 4;
    const int posl = sw * 16 + r;
    const float* xb = x + b * (CC * HW);
    const unsigned short* wbase = Wb3 + (half * 36 + kb) * 512 + r * 8;

    f32x4 acc0 = {0.f, 0.f, 0.f, 0.f};
    f32x4 acc1 = {0.f, 0.f, 0.f, 0.f};
    f32x4 acc2 = {0.f, 0.f, 0.f, 0.f};
    f32x4 acc3 = {0.f, 0.f, 0.f, 0.f};

#pragma unroll 3
    for (int s = 0; s < 9; ++s) {
        const int a  = half * 36 + s * 4 + kb;
        const int n  = a >> 3;
        const int c0 = (a & 7) * 8;
        const int slot = n * 32 + posl;
        const int base = (int)mi[slot];
        const ushort4 wq = mw[slot];
        const float w0 = frombits(wq.x), w1 = frombits(wq.y);
        const float w2 = frombits(wq.z), w3 = frombits(wq.w);
        const int i0 = iclamp(base,       0, HW - 1);
        const int i1 = iclamp(base + 129, 0, HW - 1);
        const int i2 = iclamp(base + 1,   0, HW - 1);
        const int i3 = iclamp(base + 128, 0, HW - 1);
        const float* p = xb + c0 * HW;
        bf16x8 bfrag;
#pragma unroll
        for (int j = 0; j < 8; ++j) {
            float v = p[i0] * w0;
            v = fmaf(p[i1], w1, v);
            v = fmaf(p[i2], w2, v);
            v = fmaf(p[i3], w3, v);
            bfrag[j] = (short)bfbits(v);
            p += HW;
        }
        const unsigned short* wp8 = wbase + s * 2048;
        const bf16x8 af0 = *(const bf16x8*)(wp8);
        const bf16x8 af1 = *(const bf16x8*)(wp8 + 128);
        const bf16x8 af2 = *(const bf16x8*)(wp8 + 256);
        const bf16x8 af3 = *(const bf16x8*)(wp8 + 384);
        acc0 = __builtin_amdgcn_mfma_f32_16x16x32_bf16(af0, bfrag, acc0, 0, 0, 0);
        acc1 = __builtin_amdgcn_mfma_f32_16x16x32_bf16(af1, bfrag, acc1, 0, 0, 0);
        acc2 = __builtin_amdgcn_mfma_f32_16x16x32_bf16(af2, bfrag, acc2, 0, 0, 0);
        acc3 = __builtin_amdgcn_mfma_f32_16x16x32_bf16(af3, bfrag, acc3, 0, 0, 0);
    }

    float* red = part;
    if (half) {
        *(f32x4*)&red[sw * 1024 + 0 * 256 + l * 4] = acc0;
        *(f32x4*)&red[sw * 1024 + 1 * 256 + l * 4] = acc1;
        *(f32x4*)&red[sw * 1024 + 2 * 256 + l * 4] = acc2;
        *(f32x4*)&red[sw * 1024 + 3 * 256 + l * 4] = acc3;
    }
    __syncthreads();
    if (!half) {
        acc0 += *(const f32x4*)&red[sw * 1024 + 0 * 256 + l * 4];
        acc1 += *(const f32x4*)&red[sw * 1024 + 1 * 256 + l * 4];
        acc2 += *(const f32x4*)&red[sw * 1024 + 2 * 256 + l * 4];
        acc3 += *(const f32x4*)&red[sw * 1024 + 3 * 256 + l * 4];
        const int jcol = j0 + posl;
        f32x4 av[4] = {acc0, acc1, acc2, acc3};
#pragma unroll
        for (int m = 0; m < 4; ++m)
#pragma unroll
            for (int reg = 0; reg < 4; ++reg) {
                const int oc = m * 16 + kb * 4 + reg;
                out[((b * OC + oc) * HH + i) * WW + jcol] = av[m][reg];
            }
    }
}

extern "C" void kernel_launch(void* const* d_in, const int* in_sizes, int n_in,
                              void* d_out, int out_size, void* d_ws, size_t ws_size,
                              hipStream_t stream) {
    const float* x  = (const float*)d_in[0];
    const float* Wp = (const float*)d_in[1];
    const float* bp = (const float*)d_in[2];
    const float* Wc = (const float*)d_in[3];
    float* out = (float*)d_out;
    unsigned char* ws = (unsigned char*)d_ws;
    unsigned short* Wb3 = (unsigned short*)ws;

    if (ws_size >= (size_t)WS3_NEED) {
        unsigned short* wpk = (unsigned short*)(ws + WPK_OFF3);
        unsigned short* xTb = (unsigned short*)(ws + XTB_OFF3);
        kprep<<<dim3(728), dim3(256), 0, stream>>>(x, Wc, Wp, xTb, Wb3, wpk);
        kmain<<<dim3(BB * HH * 4), dim3(256), 0, stream>>>(xTb, wpk, Wb3, bp, out);
    } else {
        wpack2fb<<<dim3((OC * 576 + 255) / 256), dim3(256), 0, stream>>>(Wc, Wb3);
        dcn_wave<<<dim3(BB * HH * 4), dim3(256), 0, stream>>>(x, Wp, bp, Wb3, out);
    }
}

// Round 20
// 40.731 us; speedup vs baseline: 3.0779x; 1.1483x over previous
//
#include <hip/hip_runtime.h>
#include <hip/hip_bf16.h>

#define BB 2
#define CC 64
#define HH 128
#define WW 128
#define OC 64
#define HW (HH * WW)

typedef __attribute__((ext_vector_type(8))) short bf16x8;
typedef __attribute__((ext_vector_type(4))) float f32x4;

__device__ __forceinline__ unsigned short bfbits(float f) {
    __hip_bfloat16 h = __float2bfloat16(f);
    return __builtin_bit_cast(unsigned short, h);
}
__device__ __forceinline__ float frombits(unsigned short u) {
    unsigned int v = ((unsigned int)u) << 16;
    return __builtin_bit_cast(float, v);
}
__device__ __forceinline__ int iclamp(int v, int lo, int hi) {
    return v < lo ? lo : (v > hi ? hi : v);
}

// ws layout (R19): Wb3 | wpk | xTb (bf16 NHWC)
#define WPK_OFF3    73728
#define XTB_OFF3    110592
#define WS3_NEED    4304896

// ---------------- fused prep: xtrans->bf16 (0..511) + wpack2 (512..655)
//                  + wppack (656..727) ----------------
__global__ __launch_bounds__(256) void kprep(
    const float* __restrict__ x,
    const float* __restrict__ Wc,
    const float* __restrict__ Wp,
    unsigned short* __restrict__ xTb,
    unsigned short* __restrict__ Wb3,
    unsigned short* __restrict__ wpk)
{
    __shared__ float tile[64 * 65];
    const int t  = threadIdx.x;
    const int bx = blockIdx.x;

    if (bx < 512) {                       // xtrans: NCHW f32 -> NHWC bf16
        const int b    = bx >> 8;
        const int pix0 = (bx & 255) * 64;
#pragma unroll
        for (int it = 0; it < 4; ++it) {
            const int item = it * 256 + t;
            const int c  = item & 63;
            const int p4 = item >> 6;
            const float4 v = *(const float4*)&x[(b * 64 + c) * 16384 + pix0 + p4 * 4];
            tile[(p4 * 4 + 0) * 65 + c] = v.x;
            tile[(p4 * 4 + 1) * 65 + c] = v.y;
            tile[(p4 * 4 + 2) * 65 + c] = v.z;
            tile[(p4 * 4 + 3) * 65 + c] = v.w;
        }
        __syncthreads();
#pragma unroll
        for (int it = 0; it < 4; ++it) {
            const int item = it * 256 + t;
            const int p  = item & 63;
            const int c4 = item >> 6;
            ushort4 v;
            v.x = bfbits(tile[p * 65 + c4 * 4 + 0]);
            v.y = bfbits(tile[p * 65 + c4 * 4 + 1]);
            v.z = bfbits(tile[p * 65 + c4 * 4 + 2]);
            v.w = bfbits(tile[p * 65 + c4 * 4 + 3]);
            *(ushort4*)&xTb[(b * 16384 + pix0 + p) * 64 + c4 * 4] = v;
        }
    } else if (bx < 656) {                // wpack2: Wc -> Wb3 A-fragment pack
        const int idx = (bx - 512) * 256 + t;
        if (idx < OC * 576) {
            const int j = idx & 7;
            const int r = (idx >> 3) & 15;
            const int m = (idx >> 7) & 3;
            const int a = idx >> 9;
            const int n = a >> 3;
            const int c = (a & 7) * 8 + j;
            const int oc = m * 16 + r;
            Wb3[idx] = bfbits(Wc[oc * 576 + c * 9 + n]);
        }
    } else {                              // wppack: Wp -> wpk (M=32, rows>=18 zero)
        const int idx = (bx - 656) * 256 + t;
        if (idx < 32 * 576) {
            const int j = idx & 7;
            const int r = (idx >> 3) & 15;
            const int m = (idx >> 7) & 1;
            const int a = idx >> 8;
            const int n = a >> 3;
            const int c = (a & 7) * 8 + j;
            const int o = m * 16 + r;
            wpk[idx] = (o < 18) ? bfbits(Wp[o * 576 + c * 9 + n]) : (unsigned short)0;
        }
    }
}

// ---------------- fused main: conv-MFMA -> metadata -> gather -> main-MFMA ---
// R20 change: odata ALIASES bbuf's head (bbuf patch content dead after phase 2;
// two extra barriers fence the alias). LDS 43.8KB -> 39.7KB => 4 blocks/CU
// (was 3, causing a ragged second generation over the 1024-block grid).
__global__ __launch_bounds__(256, 2) void kmain(
    const unsigned short* __restrict__ xTb,
    const unsigned short* __restrict__ wpk,
    const unsigned short* __restrict__ Wb3,
    const float* __restrict__ bp,
    float* __restrict__ out)
{
    __shared__ __align__(16) unsigned short bbuf[72 * 256];   // 36864 B
    __shared__ short   smi[288];                              // 576 B
    __shared__ ushort4 smw[288];                              // 2304 B
    float* const odal = (float*)bbuf;                         // alias: 32x32 f32

    const int t   = threadIdx.x;
    const int bxr = (blockIdx.x & 7) * 128 + (blockIdx.x >> 3);  // XCD swizzle
    const int b   = bxr >> 9;
    const int i   = (bxr >> 2) & 127;
    const int j0  = (bxr & 3) << 5;
    const int l   = t & 63;
    const int w   = t >> 6;
    const int sh  = l >> 5;            // slot half (0/1) for pair-staging
    const int c0  = (l & 31) * 2;      // channel pair base
    const unsigned short* xb = xTb + (((size_t)b) << 14) * 64;

    // ---- phase 1: patch staging (pure bf16 copy, 2 slots/iter) ----
#pragma unroll 6
    for (int q = 0; q < 36; ++q) {
        const int slot = w * 72 + q * 2 + sh;
        const int n   = slot >> 5;
        const int pos = slot & 31;
        const int kx = n / 3, ky = n - kx * 3;
        const int ii = i + kx - 1;
        const int jj = j0 + pos + ky - 1;
        const bool ok = ((unsigned)ii < (unsigned)HH) && ((unsigned)jj < (unsigned)WW);
        unsigned int v = 0;
        if (ok) v = *(const unsigned int*)&xb[(ii * WW + jj) * 64 + c0];
        const int row = n * 8 + (c0 >> 3);
        const int pc  = pos ^ (row & 7);
        *(unsigned int*)((char*)bbuf + row * 512 + pc * 16 + (c0 & 7) * 2) = v;
    }
    __syncthreads();

    // ---- phase 2: offset-conv MFMA (wave = oc-tile x pos-tile, K=576) ----
    {
        const int mt = w >> 1;
        const int pt = w & 1;
        const int r  = l & 15;
        const int kb = l >> 4;
        const unsigned short* wb = wpk + kb * 256 + mt * 128 + r * 8;
        f32x4 acc = {0.f, 0.f, 0.f, 0.f};
#pragma unroll 6
        for (int s = 0; s < 18; ++s) {
            const int a = s * 4 + kb;
            const bf16x8 af = *(const bf16x8*)(wb + s * 1024);
            const int pc = (pt * 16 + r) ^ (a & 7);
            const bf16x8 bf = *(const bf16x8*)&bbuf[a * 256 + pc * 8];
            acc = __builtin_amdgcn_mfma_f32_16x16x32_bf16(af, bf, acc, 0, 0, 0);
        }
        __syncthreads();               // all waves done READING bbuf
#pragma unroll
        for (int reg = 0; reg < 4; ++reg)
            odal[(mt * 16 + kb * 4 + reg) * 32 + pt * 16 + r] = acc[reg];
    }
    __syncthreads();

    // ---- phase 3: metadata (288 slots) -> LDS ----
    {
        auto mkmeta = [&](int slot) {
            const int n   = slot >> 5;
            const int pos = slot & 31;
            const int kx  = n / 3, ky = n - kx * 3;
            const float offx = odal[n * 32 + pos] + bp[n];
            const float offy = odal[(9 + n) * 32 + pos] + bp[9 + n];
            const float px = offx + (float)(kx - 1) + (float)(i + 1);
            const float py = offy + (float)(ky - 1) + (float)(j0 + pos + 1);
            const float flx = floorf(px), fly = floorf(py);
            const float qltx = fminf(fmaxf(flx,       0.f), 129.f);
            const float qlty = fminf(fmaxf(fly,       0.f), 129.f);
            const float qrbx = fminf(fmaxf(flx + 1.f, 0.f), 129.f);
            const float qrby = fminf(fmaxf(fly + 1.f, 0.f), 129.f);
            const float pxc  = fminf(fmaxf(px, 0.f), 129.f);
            const float pyc  = fminf(fmaxf(py, 0.f), 129.f);
            const float gx0 = 1.f + (qltx - pxc), gx1 = 1.f - (qrbx - pxc);
            const float gy0 = 1.f + (qlty - pyc), gy1 = 1.f - (qrby - pyc);
            const int rx0 = (int)qltx - 1, rx1 = (int)qrbx - 1;
            const int ry0 = (int)qlty - 1, ry1 = (int)qrby - 1;
            const bool vx0 = (unsigned)rx0 < (unsigned)HH, vx1 = (unsigned)rx1 < (unsigned)HH;
            const bool vy0 = (unsigned)ry0 < (unsigned)WW, vy1 = (unsigned)ry1 < (unsigned)WW;
            const float w0 = (vx0 && vy0) ? gx0 * gy0 : 0.f;   // +0
            const float w1 = (vx1 && vy1) ? gx1 * gy1 : 0.f;   // +129
            const float w2 = (vx0 && vy1) ? gx0 * gy1 : 0.f;   // +1
            const float w3 = (vx1 && vy0) ? gx1 * gy0 : 0.f;   // +128
            smi[slot] = (short)(rx0 * WW + ry0);
            smw[slot] = make_ushort4(bfbits(w0), bfbits(w1), bfbits(w2), bfbits(w3));
        };
        mkmeta(t);
        if (t < 32) mkmeta(256 + t);
    }
    __syncthreads();

    // ---- phase 4: bilinear staging (bf16 corners, 2 slots/iter) ----
#pragma unroll 6
    for (int q = 0; q < 36; ++q) {
        const int slot = w * 72 + q * 2 + sh;
        const int n   = slot >> 5;
        const int pos = slot & 31;
        const int base = (int)smi[slot];
        const ushort4 wq = smw[slot];
        const float w0 = frombits(wq.x), w1 = frombits(wq.y);
        const float w2 = frombits(wq.z), w3 = frombits(wq.w);
        const int i0 = iclamp(base,       0, HW - 1);
        const int i1 = iclamp(base + 129, 0, HW - 1);
        const int i2 = iclamp(base + 1,   0, HW - 1);
        const int i3 = iclamp(base + 128, 0, HW - 1);
        const unsigned int u0 = *(const unsigned int*)&xb[i0 * 64 + c0];
        const unsigned int u1 = *(const unsigned int*)&xb[i1 * 64 + c0];
        const unsigned int u2 = *(const unsigned int*)&xb[i2 * 64 + c0];
        const unsigned int u3 = *(const unsigned int*)&xb[i3 * 64 + c0];
        float vlo = frombits((unsigned short)u0) * w0;
        vlo = fmaf(frombits((unsigned short)u1), w1, vlo);
        vlo = fmaf(frombits((unsigned short)u2), w2, vlo);
        vlo = fmaf(frombits((unsigned short)u3), w3, vlo);
        float vhi = frombits((unsigned short)(u0 >> 16)) * w0;
        vhi = fmaf(frombits((unsigned short)(u1 >> 16)), w1, vhi);
        vhi = fmaf(frombits((unsigned short)(u2 >> 16)), w2, vhi);
        vhi = fmaf(frombits((unsigned short)(u3 >> 16)), w3, vhi);
        const unsigned int vv = (unsigned int)bfbits(vlo)
                              | ((unsigned int)bfbits(vhi) << 16);
        const int row = n * 8 + (c0 >> 3);
        const int pc  = pos ^ (row & 7);
        *(unsigned int*)((char*)bbuf + row * 512 + pc * 16 + (c0 & 7) * 2) = vv;
    }
    __syncthreads();

    // ---- phase 5: main MFMA (wave = oc-tile, 18 steps, 2 pos-tiles) ----
    {
        const int r  = l & 15;
        const int kb = l >> 4;
        const unsigned short* wbase = Wb3 + kb * 512 + w * 128 + r * 8;
        f32x4 acc0 = {0.f, 0.f, 0.f, 0.f};
        f32x4 acc1 = {0.f, 0.f, 0.f, 0.f};
#pragma unroll 3
        for (int s = 0; s < 18; ++s) {
            const int a = s * 4 + kb;
            const bf16x8 af = *(const bf16x8*)(wbase + s * 2048);
            const int pc0 = (r ^ (a & 7));
            const bf16x8 bf0 = *(const bf16x8*)&bbuf[a * 256 + pc0 * 8];
            const bf16x8 bf1 = *(const bf16x8*)&bbuf[a * 256 + (16 + pc0) * 8];
            acc0 = __builtin_amdgcn_mfma_f32_16x16x32_bf16(af, bf0, acc0, 0, 0, 0);
            acc1 = __builtin_amdgcn_mfma_f32_16x16x32_bf16(af, bf1, acc1, 0, 0, 0);
        }
#pragma unroll
        for (int reg = 0; reg < 4; ++reg) {
            const int oc = w * 16 + kb * 4 + reg;
            float* o = out + ((b * OC + oc) * HH + i) * WW + j0;
            o[r]      = acc0[reg];
            o[16 + r] = acc1[reg];
        }
    }
}

// ---------------- fallback: R13 fused kernel (proven 98.9us) ----------------
__global__ __launch_bounds__(256) void wpack2fb(const float* __restrict__ Wc,
                                                unsigned short* __restrict__ Wb3)
{
    const int idx = blockIdx.x * 256 + threadIdx.x;
    if (idx < OC * 576) {
        const int j = idx & 7;
        const int r = (idx >> 3) & 15;
        const int m = (idx >> 7) & 3;
        const int a = idx >> 9;
        const int n = a >> 3;
        const int c = (a & 7) * 8 + j;
        const int oc = m * 16 + r;
        Wb3[idx] = bfbits(Wc[oc * 576 + c * 9 + n]);
    }
}

__global__ __launch_bounds__(256, 2) void dcn_wave(
    const float* __restrict__ x,
    const float* __restrict__ Wp,
    const float* __restrict__ bp,
    const unsigned short* __restrict__ Wb3,
    float* __restrict__ out)
{
    __shared__ __align__(16) unsigned char smraw[21312];
    float*          part = (float*)smraw;
    short*          mi   = (short*)(smraw + 18432);
    ushort4*        mw   = (ushort4*)(smraw + 19008);

    const int t   = threadIdx.x;
    const int bxr = (blockIdx.x & 7) * 128 + (blockIdx.x >> 3);
    const int b   = bxr >> 9;
    const int i   = (bxr >> 2) & 127;
    const int j0  = (bxr & 3) << 5;

    {
        const int grp = t >> 5;
        const int pp  = t & 31;
        const int j   = j0 + pp;
        float acc[18];
#pragma unroll
        for (int o = 0; o < 18; ++o) acc[o] = 0.f;
        const float* xg = x + (b * CC + grp * 8) * HW;
        for (int c = 0; c < 8; ++c) {
            float xv[9];
#pragma unroll
            for (int dx = 0; dx < 3; ++dx) {
                const int ii = i + dx - 1;
                const bool okx = (unsigned)ii < (unsigned)HH;
#pragma unroll
                for (int dy = 0; dy < 3; ++dy) {
                    const int jj = j + dy - 1;
                    const bool ok = okx && ((unsigned)jj < (unsigned)WW);
                    xv[dx * 3 + dy] = ok ? xg[c * HW + ii * WW + jj] : 0.f;
                }
            }
            const float* wp = Wp + (grp * 8 + c) * 9;
#pragma unroll
            for (int o = 0; o < 18; ++o) {
                const float* w = wp + o * 576;
#pragma unroll
                for (int k = 0; k < 9; ++k)
                    acc[o] = fmaf(xv[k], w[k], acc[o]);
            }
        }
#pragma unroll
        for (int o = 0; o < 18; ++o)
            part[grp * 576 + pp * 18 + o] = acc[o];
    }
    __syncthreads();

    {
        auto mkmeta = [&](int slot) {
            const int n   = slot >> 5;
            const int pos = slot & 31;
            const int kx  = n / 3, ky = n - kx * 3;
            float offx = bp[n], offy = bp[9 + n];
#pragma unroll
            for (int g = 0; g < 8; ++g) {
                offx += part[g * 576 + pos * 18 + n];
                offy += part[g * 576 + pos * 18 + 9 + n];
            }
            const float px = offx + (float)(kx - 1) + (float)(i + 1);
            const float py = offy + (float)(ky - 1) + (float)(j0 + pos + 1);
            const float flx = floorf(px), fly = floorf(py);
            const float qltx = fminf(fmaxf(flx,       0.f), 129.f);
            const float qlty = fminf(fmaxf(fly,       0.f), 129.f);
            const float qrbx = fminf(fmaxf(flx + 1.f, 0.f), 129.f);
            const float qrby = fminf(fmaxf(fly + 1.f, 0.f), 129.f);
            const float pxc  = fminf(fmaxf(px, 0.f), 129.f);
            const float pyc  = fminf(fmaxf(py, 0.f), 129.f);
            const float gx0 = 1.f + (qltx - pxc), gx1 = 1.f - (qrbx - pxc);
            const float gy0 = 1.f + (qlty - pyc), gy1 = 1.f - (qrby - pyc);
            const int rx0 = (int)qltx - 1, rx1 = (int)qrbx - 1;
            const int ry0 = (int)qlty - 1, ry1 = (int)qrby - 1;
            const bool vx0 = (unsigned)rx0 < (unsigned)HH, vx1 = (unsigned)rx1 < (unsigned)HH;
            const bool vy0 = (unsigned)ry0 < (unsigned)WW, vy1 = (unsigned)ry1 < (unsigned)WW;
            const float w0 = (vx0 && vy0) ? gx0 * gy0 : 0.f;
            const float w1 = (vx1 && vy1) ? gx1 * gy1 : 0.f;
            const float w2 = (vx0 && vy1) ? gx0 * gy1 : 0.f;
            const float w3 = (vx1 && vy0) ? gx1 * gy0 : 0.f;
            mi[slot] = (short)(rx0 * WW + ry0);
            mw[slot] = make_ushort4(bfbits(w0), bfbits(w1), bfbits(w2), bfbits(w3));
        };
        mkmeta(t);
        if (t < 32) mkmeta(256 + t);
    }
    __syncthreads();

    const int l    = t & 63;
    const int w_   = t >> 6;
    const int sw   = w_ >> 1;
    const int half = w_ & 1;
    const int r    = l & 15;
    const int kb   = l >> 4;
    const int posl = sw * 16 + r;
    const float* xb = x + b * (CC * HW);
    const unsigned short* wbase = Wb3 + (half * 36 + kb) * 512 + r * 8;

    f32x4 acc0 = {0.f, 0.f, 0.f, 0.f};
    f32x4 acc1 = {0.f, 0.f, 0.f, 0.f};
    f32x4 acc2 = {0.f, 0.f, 0.f, 0.f};
    f32x4 acc3 = {0.f, 0.f, 0.f, 0.f};

#pragma unroll 3
    for (int s = 0; s < 9; ++s) {
        const int a  = half * 36 + s * 4 + kb;
        const int n  = a >> 3;
        const int c0 = (a & 7) * 8;
        const int slot = n * 32 + posl;
        const int base = (int)mi[slot];
        const ushort4 wq = mw[slot];
        const float w0 = frombits(wq.x), w1 = frombits(wq.y);
        const float w2 = frombits(wq.z), w3 = frombits(wq.w);
        const int i0 = iclamp(base,       0, HW - 1);
        const int i1 = iclamp(base + 129, 0, HW - 1);
        const int i2 = iclamp(base + 1,   0, HW - 1);
        const int i3 = iclamp(base + 128, 0, HW - 1);
        const float* p = xb + c0 * HW;
        bf16x8 bfrag;
#pragma unroll
        for (int j = 0; j < 8; ++j) {
            float v = p[i0] * w0;
            v = fmaf(p[i1], w1, v);
            v = fmaf(p[i2], w2, v);
            v = fmaf(p[i3], w3, v);
            bfrag[j] = (short)bfbits(v);
            p += HW;
        }
        const unsigned short* wp8 = wbase + s * 2048;
        const bf16x8 af0 = *(const bf16x8*)(wp8);
        const bf16x8 af1 = *(const bf16x8*)(wp8 + 128);
        const bf16x8 af2 = *(const bf16x8*)(wp8 + 256);
        const bf16x8 af3 = *(const bf16x8*)(wp8 + 384);
        acc0 = __builtin_amdgcn_mfma_f32_16x16x32_bf16(af0, bfrag, acc0, 0, 0, 0);
        acc1 = __builtin_amdgcn_mfma_f32_16x16x32_bf16(af1, bfrag, acc1, 0, 0, 0);
        acc2 = __builtin_amdgcn_mfma_f32_16x16x32_bf16(af2, bfrag, acc2, 0, 0, 0);
        acc3 = __builtin_amdgcn_mfma_f32_16x16x32_bf16(af3, bfrag, acc3, 0, 0, 0);
    }

    float* red = part;
    if (half) {
        *(f32x4*)&red[sw * 1024 + 0 * 256 + l * 4] = acc0;
        *(f32x4*)&red[sw * 1024 + 1 * 256 + l * 4] = acc1;
        *(f32x4*)&red[sw * 1024 + 2 * 256 + l * 4] = acc2;
        *(f32x4*)&red[sw * 1024 + 3 * 256 + l * 4] = acc3;
    }
    __syncthreads();
    if (!half) {
        acc0 += *(const f32x4*)&red[sw * 1024 + 0 * 256 + l * 4];
        acc1 += *(const f32x4*)&red[sw * 1024 + 1 * 256 + l * 4];
        acc2 += *(const f32x4*)&red[sw * 1024 + 2 * 256 + l * 4];
        acc3 += *(const f32x4*)&red[sw * 1024 + 3 * 256 + l * 4];
        const int jcol = j0 + posl;
        f32x4 av[4] = {acc0, acc1, acc2, acc3};
#pragma unroll
        for (int m = 0; m < 4; ++m)
#pragma unroll
            for (int reg = 0; reg < 4; ++reg) {
                const int oc = m * 16 + kb * 4 + reg;
                out[((b * OC + oc) * HH + i) * WW + jcol] = av[m][reg];
            }
    }
}

extern "C" void kernel_launch(void* const* d_in, const int* in_sizes, int n_in,
                              void* d_out, int out_size, void* d_ws, size_t ws_size,
                              hipStream_t stream) {
    const float* x  = (const float*)d_in[0];
    const float* Wp = (const float*)d_in[1];
    const float* bp = (const float*)d_in[2];
    const float* Wc = (const float*)d_in[3];
    float* out = (float*)d_out;
    unsigned char* ws = (unsigned char*)d_ws;
    unsigned short* Wb3 = (unsigned short*)ws;

    if (ws_size >= (size_t)WS3_NEED) {
        unsigned short* wpk = (unsigned short*)(ws + WPK_OFF3);
        unsigned short* xTb = (unsigned short*)(ws + XTB_OFF3);
        kprep<<<dim3(728), dim3(256), 0, stream>>>(x, Wc, Wp, xTb, Wb3, wpk);
        kmain<<<dim3(BB * HH * 4), dim3(256), 0, stream>>>(xTb, wpk, Wb3, bp, out);
    } else {
        wpack2fb<<<dim3((OC * 576 + 255) / 256), dim3(256), 0, stream>>>(Wc, Wb3);
        dcn_wave<<<dim3(BB * HH * 4), dim3(256), 0, stream>>>(x, Wp, bp, Wb3, out);
    }
}

// Round 21
// 38.393 us; speedup vs baseline: 3.2654x; 1.0609x over previous
//
#include <hip/hip_runtime.h>
#include <hip/hip_bf16.h>
#include <hip/hip_cooperative_groups.h>

namespace cg = cooperative_groups;

#define BB 2
#define CC 64
#define HH 128
#define WW 128
#define OC 64
#define HW (HH * WW)

typedef __attribute__((ext_vector_type(8))) short bf16x8;
typedef __attribute__((ext_vector_type(4))) float f32x4;

__device__ __forceinline__ unsigned short bfbits(float f) {
    __hip_bfloat16 h = __float2bfloat16(f);
    return __builtin_bit_cast(unsigned short, h);
}
__device__ __forceinline__ float frombits(unsigned short u) {
    unsigned int v = ((unsigned int)u) << 16;
    return __builtin_bit_cast(float, v);
}
__device__ __forceinline__ int iclamp(int v, int lo, int hi) {
    return v < lo ? lo : (v > hi ? hi : v);
}

// ws layout: Wb3 | wpk | xTb (bf16 NHWC)
#define WPK_OFF3    73728
#define XTB_OFF3    110592
#define WS3_NEED    4304896

// ================= shared device sections =================

__device__ __forceinline__ void prep_section(
    int bx, int t, float* tile,
    const float* __restrict__ x, const float* __restrict__ Wc,
    const float* __restrict__ Wp,
    unsigned short* __restrict__ xTb, unsigned short* __restrict__ Wb3,
    unsigned short* __restrict__ wpk)
{
    if (bx < 512) {                       // xtrans: NCHW f32 -> NHWC bf16
        const int b    = bx >> 8;
        const int pix0 = (bx & 255) * 64;
#pragma unroll
        for (int it = 0; it < 4; ++it) {
            const int item = it * 256 + t;
            const int c  = item & 63;
            const int p4 = item >> 6;
            const float4 v = *(const float4*)&x[(b * 64 + c) * 16384 + pix0 + p4 * 4];
            tile[(p4 * 4 + 0) * 65 + c] = v.x;
            tile[(p4 * 4 + 1) * 65 + c] = v.y;
            tile[(p4 * 4 + 2) * 65 + c] = v.z;
            tile[(p4 * 4 + 3) * 65 + c] = v.w;
        }
        __syncthreads();
#pragma unroll
        for (int it = 0; it < 4; ++it) {
            const int item = it * 256 + t;
            const int p  = item & 63;
            const int c4 = item >> 6;
            ushort4 v;
            v.x = bfbits(tile[p * 65 + c4 * 4 + 0]);
            v.y = bfbits(tile[p * 65 + c4 * 4 + 1]);
            v.z = bfbits(tile[p * 65 + c4 * 4 + 2]);
            v.w = bfbits(tile[p * 65 + c4 * 4 + 3]);
            *(ushort4*)&xTb[(b * 16384 + pix0 + p) * 64 + c4 * 4] = v;
        }
    } else if (bx < 656) {                // wpack2: Wc -> Wb3 A-fragment pack
        const int idx = (bx - 512) * 256 + t;
        if (idx < OC * 576) {
            const int j = idx & 7;
            const int r = (idx >> 3) & 15;
            const int m = (idx >> 7) & 3;
            const int a = idx >> 9;
            const int n = a >> 3;
            const int c = (a & 7) * 8 + j;
            const int oc = m * 16 + r;
            Wb3[idx] = bfbits(Wc[oc * 576 + c * 9 + n]);
        }
    } else if (bx < 728) {                // wppack: Wp -> wpk (M=32, rows>=18 zero)
        const int idx = (bx - 656) * 256 + t;
        if (idx < 32 * 576) {
            const int j = idx & 7;
            const int r = (idx >> 3) & 15;
            const int m = (idx >> 7) & 1;
            const int a = idx >> 8;
            const int n = a >> 3;
            const int c = (a & 7) * 8 + j;
            const int o = m * 16 + r;
            wpk[idx] = (o < 18) ? bfbits(Wp[o * 576 + c * 9 + n]) : (unsigned short)0;
        }
    }
}

// 5-phase main body (R20-proven): conv-MFMA -> metadata -> gather -> main-MFMA
__device__ __forceinline__ void main_section(
    int bxl, int t, unsigned char* smem,
    const unsigned short* __restrict__ xTb,
    const unsigned short* __restrict__ wpk,
    const unsigned short* __restrict__ Wb3,
    const float* __restrict__ bp,
    float* __restrict__ out)
{
    unsigned short* bbuf = (unsigned short*)smem;             // 36864 B
    short*   smi = (short*)(smem + 36864);                    // 576 B
    ushort4* smw = (ushort4*)(smem + 37440);                  // 2304 B
    float* const odal = (float*)smem;                         // alias: 32x32 f32

    const int bxr = (bxl & 7) * 128 + (bxl >> 3);             // XCD swizzle
    const int b   = bxr >> 9;
    const int i   = (bxr >> 2) & 127;
    const int j0  = (bxr & 3) << 5;
    const int l   = t & 63;
    const int w   = t >> 6;
    const int sh  = l >> 5;
    const int c0  = (l & 31) * 2;
    const unsigned short* xb = xTb + (((size_t)b) << 14) * 64;

    // ---- phase 1: patch staging (pure bf16 copy, 2 slots/iter) ----
#pragma unroll 6
    for (int q = 0; q < 36; ++q) {
        const int slot = w * 72 + q * 2 + sh;
        const int n   = slot >> 5;
        const int pos = slot & 31;
        const int kx = n / 3, ky = n - kx * 3;
        const int ii = i + kx - 1;
        const int jj = j0 + pos + ky - 1;
        const bool ok = ((unsigned)ii < (unsigned)HH) && ((unsigned)jj < (unsigned)WW);
        unsigned int v = 0;
        if (ok) v = *(const unsigned int*)&xb[(ii * WW + jj) * 64 + c0];
        const int row = n * 8 + (c0 >> 3);
        const int pc  = pos ^ (row & 7);
        *(unsigned int*)((char*)bbuf + row * 512 + pc * 16 + (c0 & 7) * 2) = v;
    }
    __syncthreads();

    // ---- phase 2: offset-conv MFMA ----
    {
        const int mt = w >> 1;
        const int pt = w & 1;
        const int r  = l & 15;
        const int kb = l >> 4;
        const unsigned short* wb = wpk + kb * 256 + mt * 128 + r * 8;
        f32x4 acc = {0.f, 0.f, 0.f, 0.f};
#pragma unroll 6
        for (int s = 0; s < 18; ++s) {
            const int a = s * 4 + kb;
            const bf16x8 af = *(const bf16x8*)(wb + s * 1024);
            const int pc = (pt * 16 + r) ^ (a & 7);
            const bf16x8 bf = *(const bf16x8*)&bbuf[a * 256 + pc * 8];
            acc = __builtin_amdgcn_mfma_f32_16x16x32_bf16(af, bf, acc, 0, 0, 0);
        }
        __syncthreads();               // all waves done READING bbuf
#pragma unroll
        for (int reg = 0; reg < 4; ++reg)
            odal[(mt * 16 + kb * 4 + reg) * 32 + pt * 16 + r] = acc[reg];
    }
    __syncthreads();

    // ---- phase 3: metadata (288 slots) -> LDS ----
    {
        auto mkmeta = [&](int slot) {
            const int n   = slot >> 5;
            const int pos = slot & 31;
            const int kx  = n / 3, ky = n - kx * 3;
            const float offx = odal[n * 32 + pos] + bp[n];
            const float offy = odal[(9 + n) * 32 + pos] + bp[9 + n];
            const float px = offx + (float)(kx - 1) + (float)(i + 1);
            const float py = offy + (float)(ky - 1) + (float)(j0 + pos + 1);
            const float flx = floorf(px), fly = floorf(py);
            const float qltx = fminf(fmaxf(flx,       0.f), 129.f);
            const float qlty = fminf(fmaxf(fly,       0.f), 129.f);
            const float qrbx = fminf(fmaxf(flx + 1.f, 0.f), 129.f);
            const float qrby = fminf(fmaxf(fly + 1.f, 0.f), 129.f);
            const float pxc  = fminf(fmaxf(px, 0.f), 129.f);
            const float pyc  = fminf(fmaxf(py, 0.f), 129.f);
            const float gx0 = 1.f + (qltx - pxc), gx1 = 1.f - (qrbx - pxc);
            const float gy0 = 1.f + (qlty - pyc), gy1 = 1.f - (qrby - pyc);
            const int rx0 = (int)qltx - 1, rx1 = (int)qrbx - 1;
            const int ry0 = (int)qlty - 1, ry1 = (int)qrby - 1;
            const bool vx0 = (unsigned)rx0 < (unsigned)HH, vx1 = (unsigned)rx1 < (unsigned)HH;
            const bool vy0 = (unsigned)ry0 < (unsigned)WW, vy1 = (unsigned)ry1 < (unsigned)WW;
            const float w0 = (vx0 && vy0) ? gx0 * gy0 : 0.f;   // +0
            const float w1 = (vx1 && vy1) ? gx1 * gy1 : 0.f;   // +129
            const float w2 = (vx0 && vy1) ? gx0 * gy1 : 0.f;   // +1
            const float w3 = (vx1 && vy0) ? gx1 * gy0 : 0.f;   // +128
            smi[slot] = (short)(rx0 * WW + ry0);
            smw[slot] = make_ushort4(bfbits(w0), bfbits(w1), bfbits(w2), bfbits(w3));
        };
        mkmeta(t);
        if (t < 32) mkmeta(256 + t);
    }
    __syncthreads();

    // ---- phase 4: bilinear staging (bf16 corners, 2 slots/iter) ----
#pragma unroll 6
    for (int q = 0; q < 36; ++q) {
        const int slot = w * 72 + q * 2 + sh;
        const int n   = slot >> 5;
        const int pos = slot & 31;
        const int base = (int)smi[slot];
        const ushort4 wq = smw[slot];
        const float w0 = frombits(wq.x), w1 = frombits(wq.y);
        const float w2 = frombits(wq.z), w3 = frombits(wq.w);
        const int i0 = iclamp(base,       0, HW - 1);
        const int i1 = iclamp(base + 129, 0, HW - 1);
        const int i2 = iclamp(base + 1,   0, HW - 1);
        const int i3 = iclamp(base + 128, 0, HW - 1);
        const unsigned int u0 = *(const unsigned int*)&xb[i0 * 64 + c0];
        const unsigned int u1 = *(const unsigned int*)&xb[i1 * 64 + c0];
        const unsigned int u2 = *(const unsigned int*)&xb[i2 * 64 + c0];
        const unsigned int u3 = *(const unsigned int*)&xb[i3 * 64 + c0];
        float vlo = frombits((unsigned short)u0) * w0;
        vlo = fmaf(frombits((unsigned short)u1), w1, vlo);
        vlo = fmaf(frombits((unsigned short)u2), w2, vlo);
        vlo = fmaf(frombits((unsigned short)u3), w3, vlo);
        float vhi = frombits((unsigned short)(u0 >> 16)) * w0;
        vhi = fmaf(frombits((unsigned short)(u1 >> 16)), w1, vhi);
        vhi = fmaf(frombits((unsigned short)(u2 >> 16)), w2, vhi);
        vhi = fmaf(frombits((unsigned short)(u3 >> 16)), w3, vhi);
        const unsigned int vv = (unsigned int)bfbits(vlo)
                              | ((unsigned int)bfbits(vhi) << 16);
        const int row = n * 8 + (c0 >> 3);
        const int pc  = pos ^ (row & 7);
        *(unsigned int*)((char*)bbuf + row * 512 + pc * 16 + (c0 & 7) * 2) = vv;
    }
    __syncthreads();

    // ---- phase 5: main MFMA (wave = oc-tile, 18 steps, 2 pos-tiles) ----
    {
        const int r  = l & 15;
        const int kb = l >> 4;
        const unsigned short* wbase = Wb3 + kb * 512 + w * 128 + r * 8;
        f32x4 acc0 = {0.f, 0.f, 0.f, 0.f};
        f32x4 acc1 = {0.f, 0.f, 0.f, 0.f};
#pragma unroll 3
        for (int s = 0; s < 18; ++s) {
            const int a = s * 4 + kb;
            const bf16x8 af = *(const bf16x8*)(wbase + s * 2048);
            const int pc0 = (r ^ (a & 7));
            const bf16x8 bf0 = *(const bf16x8*)&bbuf[a * 256 + pc0 * 8];
            const bf16x8 bf1 = *(const bf16x8*)&bbuf[a * 256 + (16 + pc0) * 8];
            acc0 = __builtin_amdgcn_mfma_f32_16x16x32_bf16(af, bf0, acc0, 0, 0, 0);
            acc1 = __builtin_amdgcn_mfma_f32_16x16x32_bf16(af, bf1, acc1, 0, 0, 0);
        }
#pragma unroll
        for (int reg = 0; reg < 4; ++reg) {
            const int oc = w * 16 + kb * 4 + reg;
            float* o = out + ((b * OC + oc) * HH + i) * WW + j0;
            o[r]      = acc0[reg];
            o[16 + r] = acc1[reg];
        }
    }
}

// ================= cooperative fused kernel (1 dispatch) =================
__global__ __launch_bounds__(256, 2) void kfused(
    const float* __restrict__ x,
    const float* __restrict__ Wc,
    const float* __restrict__ Wp,
    const float* __restrict__ bp,
    unsigned short* __restrict__ xTb,
    unsigned short* __restrict__ Wb3,
    unsigned short* __restrict__ wpk,
    float* __restrict__ out)
{
    __shared__ __align__(16) unsigned char smem[39744];   // union: tile / bbuf+meta
    const int t  = threadIdx.x;
    const int bx = blockIdx.x;

    prep_section(bx, t, (float*)smem, x, Wc, Wp, xTb, Wb3, wpk);

    __threadfence();
    cg::this_grid().sync();

    main_section(bx, t, smem, xTb, wpk, Wb3, bp, out);
}

// ================= non-cooperative fallback (R20-proven, 40.7us) =========
__global__ __launch_bounds__(256) void kprep(
    const float* __restrict__ x,
    const float* __restrict__ Wc,
    const float* __restrict__ Wp,
    unsigned short* __restrict__ xTb,
    unsigned short* __restrict__ Wb3,
    unsigned short* __restrict__ wpk)
{
    __shared__ float tile[64 * 65];
    prep_section(blockIdx.x, threadIdx.x, tile, x, Wc, Wp, xTb, Wb3, wpk);
}

__global__ __launch_bounds__(256, 2) void kmain(
    const unsigned short* __restrict__ xTb,
    const unsigned short* __restrict__ wpk,
    const unsigned short* __restrict__ Wb3,
    const float* __restrict__ bp,
    float* __restrict__ out)
{
    __shared__ __align__(16) unsigned char smem[39744];
    main_section(blockIdx.x, threadIdx.x, smem, xTb, wpk, Wb3, bp, out);
}

extern "C" void kernel_launch(void* const* d_in, const int* in_sizes, int n_in,
                              void* d_out, int out_size, void* d_ws, size_t ws_size,
                              hipStream_t stream) {
    const float* x  = (const float*)d_in[0];
    const float* Wp = (const float*)d_in[1];
    const float* bp = (const float*)d_in[2];
    const float* Wc = (const float*)d_in[3];
    float* out = (float*)d_out;
    unsigned char* ws = (unsigned char*)d_ws;
    unsigned short* Wb3 = (unsigned short*)ws;
    unsigned short* wpk = (unsigned short*)(ws + WPK_OFF3);
    unsigned short* xTb = (unsigned short*)(ws + XTB_OFF3);

    // deterministic, capture-safe queries: can the whole 1024-block grid co-reside?
    int maxb = 0, ncu = 0, dev = 0;
    hipGetDevice(&dev);
    hipDeviceGetAttribute(&ncu, hipDeviceAttributeMultiprocessorCount, dev);
    hipOccupancyMaxActiveBlocksPerMultiprocessor(&maxb, (const void*)kfused, 256, 0);
    bool coop = ((long)maxb * ncu >= BB * HH * 4);

    if (coop) {
        void* args[] = {(void*)&x, (void*)&Wc, (void*)&Wp, (void*)&bp,
                        (void*)&xTb, (void*)&Wb3, (void*)&wpk, (void*)&out};
        hipError_t e = hipLaunchCooperativeKernel((const void*)kfused,
                                                  dim3(BB * HH * 4), dim3(256),
                                                  args, 0, stream);
        if (e == hipSuccess) return;
        // fall through to 2-kernel path on launch failure
    }
    kprep<<<dim3(728), dim3(256), 0, stream>>>(x, Wc, Wp, xTb, Wb3, wpk);
    kmain<<<dim3(BB * HH * 4), dim3(256), 0, stream>>>(xTb, wpk, Wb3, bp, out);
}